// Round 1
// baseline (615.614 us; speedup 1.0000x reference)
//
#include <hip/hip_runtime.h>
#include <hip/hip_bf16.h>
#include <cstddef>

// Problem constants (from reference): T tokens, D dim, N spans, W max width.
constexpr int Tt = 8192;
constexpr int Dd = 768;
constexpr int Nn = 10000;
constexpr int Ww = 32;

// ---------------------------------------------------------------------------
// Kernel A: Q[t][e] = sum_d emb[t][d] * Wq[e][d] + bq[e]   (NT fp32 GEMM)
// M=8192, N=768, K=768. 64x64 block tile, BK=32, 256 threads, 4x4 micro-tile.
// LDS columns XOR-swizzled at float4 granularity -> conflict-free ds_read_b128.
// ---------------------------------------------------------------------------
__global__ __launch_bounds__(256) void qproj_kernel(const float* __restrict__ emb,
                                                    const float* __restrict__ Wq,
                                                    const float* __restrict__ bq,
                                                    float* __restrict__ Q) {
    __shared__ float As[64][32];
    __shared__ float Bs[64][32];
    const int tid = threadIdx.x;
    const int tx = tid & 15;   // output col group (e)
    const int ty = tid >> 4;   // output row group (t)
    const int m0 = blockIdx.x * 64;
    const int n0 = blockIdx.y * 64;

    float acc[4][4] = {};

    for (int kc = 0; kc < Dd; kc += 32) {
        // Stage 64x32 tiles of A (emb) and B (Wq). 512 float4 per tile, 2/thread.
#pragma unroll
        for (int i = 0; i < 2; ++i) {
            const int f   = tid + i * 256;
            const int row = f >> 3;
            const int c4  = f & 7;
            const int ph  = (c4 + (row >> 2)) & 7;  // XOR-ish swizzle
            *reinterpret_cast<float4*>(&As[row][ph * 4]) =
                *reinterpret_cast<const float4*>(&emb[(size_t)(m0 + row) * Dd + kc + c4 * 4]);
            *reinterpret_cast<float4*>(&Bs[row][ph * 4]) =
                *reinterpret_cast<const float4*>(&Wq[(size_t)(n0 + row) * Dd + kc + c4 * 4]);
        }
        __syncthreads();

#pragma unroll
        for (int d4 = 0; d4 < 8; ++d4) {
            float4 av[4], bv[4];
#pragma unroll
            for (int r = 0; r < 4; ++r)
                av[r] = *reinterpret_cast<const float4*>(&As[ty * 4 + r][((d4 + ty) & 7) * 4]);
#pragma unroll
            for (int c = 0; c < 4; ++c)
                bv[c] = *reinterpret_cast<const float4*>(&Bs[tx * 4 + c][((d4 + tx) & 7) * 4]);
#pragma unroll
            for (int r = 0; r < 4; ++r)
#pragma unroll
                for (int c = 0; c < 4; ++c) {
                    acc[r][c] += av[r].x * bv[c].x;
                    acc[r][c] += av[r].y * bv[c].y;
                    acc[r][c] += av[r].z * bv[c].z;
                    acc[r][c] += av[r].w * bv[c].w;
                }
        }
        __syncthreads();
    }

#pragma unroll
    for (int r = 0; r < 4; ++r) {
        float4 o;
        o.x = acc[r][0] + bq[n0 + tx * 4 + 0];
        o.y = acc[r][1] + bq[n0 + tx * 4 + 1];
        o.z = acc[r][2] + bq[n0 + tx * 4 + 2];
        o.w = acc[r][3] + bq[n0 + tx * 4 + 3];
        *reinterpret_cast<float4*>(&Q[(size_t)(m0 + ty * 4 + r) * Dd + n0 + tx * 4]) = o;
    }
}

// ---------------------------------------------------------------------------
// Kernel B: per-span attention, one wave (64 lanes) per span, 4 spans/block.
// S[q][k] = Q[start+q] . emb[start+k]  (full 32x32 tile, D chunked by 32)
// softmax rows (k<L), c[k] = sum_q w[q][k], out[n] = sum_k c[k]*emb[start+k].
// Note: starts < T-W so start+31 <= 8190 < T -> no clipping ever needed.
// ---------------------------------------------------------------------------
__global__ __launch_bounds__(256) void span_attn_kernel(const float* __restrict__ emb,
                                                        const int* __restrict__ spans,
                                                        const float* __restrict__ Q,
                                                        float* __restrict__ out) {
    __shared__ float smem[4][2][32][32];  // per wave: Qc | Ec (8 KB)
    __shared__ float Cs[4][32];

    const int wave = threadIdx.x >> 6;
    const int lane = threadIdx.x & 63;
    const int s    = blockIdx.x * 4 + wave;  // N = 2500*4 exactly

    const int start = spans[2 * s];
    const int L     = spans[2 * s + 1] - start + 1;  // 1..32

    const int lr = lane >> 3;  // q group
    const int lc = lane & 7;   // k group

    float (*Qc)[32] = smem[wave][0];
    float (*Ec)[32] = smem[wave][1];

    float acc[4][4] = {};

    for (int kc = 0; kc < Dd; kc += 32) {
        // Stage rows < L only (rows >= L are never consumed).
#pragma unroll
        for (int i = 0; i < 4; ++i) {
            const int f   = lane + i * 64;
            const int row = f >> 3;
            const int c4  = f & 7;
            if (row < L) {
                const int ph = (c4 + (row >> 2)) & 7;
                *reinterpret_cast<float4*>(&Qc[row][ph * 4]) =
                    *reinterpret_cast<const float4*>(&Q[(size_t)(start + row) * Dd + kc + c4 * 4]);
                *reinterpret_cast<float4*>(&Ec[row][ph * 4]) =
                    *reinterpret_cast<const float4*>(&emb[(size_t)(start + row) * Dd + kc + c4 * 4]);
            }
        }
        __syncthreads();

#pragma unroll
        for (int d4 = 0; d4 < 8; ++d4) {
            float4 av[4], bv[4];
#pragma unroll
            for (int r = 0; r < 4; ++r)
                av[r] = *reinterpret_cast<const float4*>(&Qc[lr * 4 + r][((d4 + lr) & 7) * 4]);
#pragma unroll
            for (int c = 0; c < 4; ++c)
                bv[c] = *reinterpret_cast<const float4*>(&Ec[lc * 4 + c][((d4 + lc) & 7) * 4]);
#pragma unroll
            for (int r = 0; r < 4; ++r)
#pragma unroll
                for (int c = 0; c < 4; ++c) {
                    acc[r][c] += av[r].x * bv[c].x;
                    acc[r][c] += av[r].y * bv[c].y;
                    acc[r][c] += av[r].z * bv[c].z;
                    acc[r][c] += av[r].w * bv[c].w;
                }
        }
        __syncthreads();
    }

    // Scores -> LDS (stride 33, overlaps Qc/Ec which are dead now).
    float* Ss = &smem[wave][0][0][0];  // needs 32*33 = 1056 floats <= 2048
#pragma unroll
    for (int r = 0; r < 4; ++r)
#pragma unroll
        for (int c = 0; c < 4; ++c)
            Ss[(lr * 4 + r) * 33 + (lc * 4 + c)] = acc[r][c];
    __syncthreads();

    // Row softmax over valid k (lanes 0..31 each own a row).
    if (lane < 32 && lane < L) {
        float m = -1e30f;
        for (int k = 0; k < L; ++k) m = fmaxf(m, Ss[lane * 33 + k]);
        float sum = 0.f;
        for (int k = 0; k < L; ++k) {
            const float e = __expf(Ss[lane * 33 + k] - m);
            Ss[lane * 33 + k] = e;
            sum += e;
        }
        const float inv = 1.f / sum;
        for (int k = 0; k < L; ++k) Ss[lane * 33 + k] *= inv;
    }
    __syncthreads();

    // Column sums c[k] = sum_{q<L} w[q][k].
    if (lane < 32) {
        float c = 0.f;
        if (lane < L)
            for (int q = 0; q < L; ++q) c += Ss[q * 33 + lane];
        Cs[wave][lane] = c;
    }
    __syncthreads();

    // out[s][d] = sum_{k<L} c[k] * emb[start+k][d], coalesced over lanes.
#pragma unroll
    for (int i = 0; i < Dd / 64; ++i) {
        const int d = i * 64 + lane;
        float v = 0.f;
        for (int k = 0; k < L; ++k)
            v += Cs[wave][k] * emb[(size_t)(start + k) * Dd + d];
        out[(size_t)s * Dd + d] = v;
    }
}

// ---------------------------------------------------------------------------
extern "C" void kernel_launch(void* const* d_in, const int* in_sizes, int n_in,
                              void* d_out, int out_size, void* d_ws, size_t ws_size,
                              hipStream_t stream) {
    const float* emb   = (const float*)d_in[0];  // (T, D) fp32
    const int*   spans = (const int*)d_in[1];    // (N, 2) int32
    const float* Wq    = (const float*)d_in[2];  // (D, D) fp32
    const float* bq    = (const float*)d_in[3];  // (D,)  fp32
    float*       out   = (float*)d_out;          // (N, D) fp32
    float*       Q     = (float*)d_ws;           // (T, D) fp32 scratch, 25.2 MB

    qproj_kernel<<<dim3(Tt / 64, Dd / 64), 256, 0, stream>>>(emb, Wq, bq, Q);
    span_attn_kernel<<<dim3(Nn / 4), 256, 0, stream>>>(emb, spans, Q, out);
}

// Round 2
// 475.619 us; speedup vs baseline: 1.2943x; 1.2943x over previous
//
#include <hip/hip_runtime.h>
#include <hip/hip_bf16.h>
#include <cstddef>
#include <cstdint>

constexpr int Tt = 8192;
constexpr int Dd = 768;
constexpr int Nn = 10000;
constexpr int Ww = 32;

typedef __bf16 bf16x8 __attribute__((ext_vector_type(8)));
typedef __bf16 bf16x4 __attribute__((ext_vector_type(4)));
typedef __bf16 bf16x2 __attribute__((ext_vector_type(2)));
typedef float f32x4 __attribute__((ext_vector_type(4)));

#define MFMA16(a, b, c) __builtin_amdgcn_mfma_f32_16x16x32_bf16((a), (b), (c), 0, 0, 0)

// ---------------------------------------------------------------------------
// Kernel A: Q = emb @ Wq^T + bq  (fp32 accumulate — best precision), emitted
// as bf16 hi (and optional lo) parts for the MFMA score kernel.
// 64x64 tile, BK=32, 256 threads, 4x4 micro-tile, swizzled LDS.
// ---------------------------------------------------------------------------
template <bool SPLIT>
__global__ __launch_bounds__(256) void qproj_kernel(const float* __restrict__ emb,
                                                    const float* __restrict__ Wq,
                                                    const float* __restrict__ bq,
                                                    __bf16* __restrict__ Qh,
                                                    __bf16* __restrict__ Ql) {
    __shared__ float As[64][32];
    __shared__ float Bs[64][32];
    const int tid = threadIdx.x;
    const int tx = tid & 15;
    const int ty = tid >> 4;
    const int m0 = blockIdx.x * 64;
    const int n0 = blockIdx.y * 64;

    float acc[4][4] = {};

    for (int kc = 0; kc < Dd; kc += 32) {
#pragma unroll
        for (int i = 0; i < 2; ++i) {
            const int f   = tid + i * 256;
            const int row = f >> 3;
            const int c4  = f & 7;
            const int ph  = (c4 + (row >> 2)) & 7;
            *reinterpret_cast<float4*>(&As[row][ph * 4]) =
                *reinterpret_cast<const float4*>(&emb[(size_t)(m0 + row) * Dd + kc + c4 * 4]);
            *reinterpret_cast<float4*>(&Bs[row][ph * 4]) =
                *reinterpret_cast<const float4*>(&Wq[(size_t)(n0 + row) * Dd + kc + c4 * 4]);
        }
        __syncthreads();

#pragma unroll
        for (int d4 = 0; d4 < 8; ++d4) {
            float4 av[4], bv[4];
#pragma unroll
            for (int r = 0; r < 4; ++r)
                av[r] = *reinterpret_cast<const float4*>(&As[ty * 4 + r][((d4 + ty) & 7) * 4]);
#pragma unroll
            for (int c = 0; c < 4; ++c)
                bv[c] = *reinterpret_cast<const float4*>(&Bs[tx * 4 + c][((d4 + tx) & 7) * 4]);
#pragma unroll
            for (int r = 0; r < 4; ++r)
#pragma unroll
                for (int c = 0; c < 4; ++c) {
                    acc[r][c] += av[r].x * bv[c].x;
                    acc[r][c] += av[r].y * bv[c].y;
                    acc[r][c] += av[r].z * bv[c].z;
                    acc[r][c] += av[r].w * bv[c].w;
                }
        }
        __syncthreads();
    }

#pragma unroll
    for (int r = 0; r < 4; ++r) {
        bf16x4 oh, ol;
#pragma unroll
        for (int c = 0; c < 4; ++c) {
            const float v = acc[r][c] + bq[n0 + tx * 4 + c];
            const __bf16 h = (__bf16)v;
            oh[c] = h;
            if (SPLIT) ol[c] = (__bf16)(v - (float)h);
        }
        const size_t off = (size_t)(m0 + ty * 4 + r) * Dd + n0 + tx * 4;
        *reinterpret_cast<bf16x4*>(&Qh[off]) = oh;
        if (SPLIT) *reinterpret_cast<bf16x4*>(&Ql[off]) = ol;
    }
}

// ---------------------------------------------------------------------------
// emb fp32 -> bf16 converter (one float4 -> bf16x4 per thread).
// ---------------------------------------------------------------------------
__global__ __launch_bounds__(256) void conv_kernel(const float* __restrict__ emb,
                                                   __bf16* __restrict__ Eb) {
    const int i = blockIdx.x * 256 + threadIdx.x;  // Tt*Dd/4 threads exactly
    const float4 v = reinterpret_cast<const float4*>(emb)[i];
    bf16x4 o;
    o[0] = (__bf16)v.x; o[1] = (__bf16)v.y; o[2] = (__bf16)v.z; o[3] = (__bf16)v.w;
    reinterpret_cast<bf16x4*>(Eb)[i] = o;
}

// ---------------------------------------------------------------------------
// Kernel B: one wave per span. Scores via mfma_f32_16x16x32_bf16, fragments
// loaded DIRECTLY from global (A/B layout: [m=lane&15][k=(lane>>4)*8+j]).
// If L<=16 only one 16x16 tile is computed (wave-uniform branch).
// Softmax + column-sum in LDS, output = sum_k c_k * E[start+k] (bf16 reads).
// C/D layout: col=lane&15, row=(lane>>4)*4+reg.
// ---------------------------------------------------------------------------
template <bool SPLIT>
__global__ __launch_bounds__(256) void span_attn_kernel(const __bf16* __restrict__ Eb,
                                                        const int* __restrict__ spans,
                                                        const __bf16* __restrict__ Qh,
                                                        const __bf16* __restrict__ Ql,
                                                        float* __restrict__ out) {
    __shared__ float Ss[4][32 * 33];
    __shared__ float Cs[4][32];

    const int wave = threadIdx.x >> 6;
    const int lane = threadIdx.x & 63;
    const int s    = blockIdx.x * 4 + wave;  // Nn = 2500*4

    const int start = spans[2 * s];
    const int L     = spans[2 * s + 1] - start + 1;  // 1..32
    const bool big  = L > 16;

    const int row = lane & 15;
    const int kq  = lane >> 4;

    const size_t rbase = (size_t)(start + row) * Dd + kq * 8;
    const __bf16* qh0 = Qh + rbase;
    const __bf16* eb0 = Eb + rbase;
    const __bf16* ql0 = SPLIT ? (Ql + rbase) : nullptr;

    f32x4 acc00 = {0.f, 0.f, 0.f, 0.f};
    f32x4 acc01 = {0.f, 0.f, 0.f, 0.f};
    f32x4 acc10 = {0.f, 0.f, 0.f, 0.f};
    f32x4 acc11 = {0.f, 0.f, 0.f, 0.f};

    for (int k0 = 0; k0 < Dd; k0 += 32) {
        const bf16x8 a0 = *reinterpret_cast<const bf16x8*>(qh0 + k0);
        const bf16x8 b0 = *reinterpret_cast<const bf16x8*>(eb0 + k0);
        acc00 = MFMA16(a0, b0, acc00);
        bf16x8 al0;
        if (SPLIT) {
            al0 = *reinterpret_cast<const bf16x8*>(ql0 + k0);
            acc00 = MFMA16(al0, b0, acc00);
        }
        if (big) {
            const bf16x8 a1 = *reinterpret_cast<const bf16x8*>(qh0 + 16 * Dd + k0);
            const bf16x8 b1 = *reinterpret_cast<const bf16x8*>(eb0 + 16 * Dd + k0);
            acc01 = MFMA16(a0, b1, acc01);
            acc10 = MFMA16(a1, b0, acc10);
            acc11 = MFMA16(a1, b1, acc11);
            if (SPLIT) {
                const bf16x8 al1 = *reinterpret_cast<const bf16x8*>(ql0 + 16 * Dd + k0);
                acc01 = MFMA16(al0, b1, acc01);
                acc10 = MFMA16(al1, b0, acc10);
                acc11 = MFMA16(al1, b1, acc11);
            }
        }
    }

    // Scatter scores to LDS: S[q][k] at stride 33.
    float* S_ = Ss[wave];
#pragma unroll
    for (int r = 0; r < 4; ++r) {
        const int q = kq * 4 + r;
        S_[q * 33 + row] = acc00[r];
        if (big) {
            S_[q * 33 + 16 + row]        = acc01[r];
            S_[(16 + q) * 33 + row]      = acc10[r];
            S_[(16 + q) * 33 + 16 + row] = acc11[r];
        }
    }
    __syncthreads();

    // Row softmax (lane < 32 owns row `lane`).
    if (lane < 32 && lane < L) {
        float m = -1e30f;
        for (int k = 0; k < L; ++k) m = fmaxf(m, S_[lane * 33 + k]);
        float sum = 0.f;
        for (int k = 0; k < L; ++k) {
            const float e = __expf(S_[lane * 33 + k] - m);
            S_[lane * 33 + k] = e;
            sum += e;
        }
        const float inv = 1.f / sum;
        for (int k = 0; k < L; ++k) S_[lane * 33 + k] *= inv;
    }
    __syncthreads();

    // Column sums c[k] = sum_{q<L} w[q][k].
    if (lane < 32) {
        float c = 0.f;
        if (lane < L)
            for (int q = 0; q < L; ++q) c += S_[q * 33 + lane];
        Cs[wave][lane] = c;
    }
    __syncthreads();

    // out[s][d] = sum_{k<L} c[k] * E[start+k][d]; 2 bf16 per lane per iter.
#pragma unroll
    for (int i = 0; i < Dd / 128; ++i) {
        const int d = i * 128 + lane * 2;
        float vx = 0.f, vy = 0.f;
        for (int k = 0; k < L; ++k) {
            const float c = Cs[wave][k];
            const bf16x2 e = *reinterpret_cast<const bf16x2*>(&Eb[(size_t)(start + k) * Dd + d]);
            vx += c * (float)e[0];
            vy += c * (float)e[1];
        }
        float2 o; o.x = vx; o.y = vy;
        *reinterpret_cast<float2*>(&out[(size_t)s * Dd + d]) = o;
    }
}

// ---------------------------------------------------------------------------
extern "C" void kernel_launch(void* const* d_in, const int* in_sizes, int n_in,
                              void* d_out, int out_size, void* d_ws, size_t ws_size,
                              hipStream_t stream) {
    const float* emb   = (const float*)d_in[0];
    const int*   spans = (const int*)d_in[1];
    const float* Wq    = (const float*)d_in[2];
    const float* bq    = (const float*)d_in[3];
    float*       out   = (float*)d_out;

    const size_t TD = (size_t)Tt * Dd;
    __bf16* w = (__bf16*)d_ws;

    // split mode (Q hi+lo bf16 pair halves score error) needs 3*TD bf16.
    const bool split = ws_size >= 3 * TD * sizeof(__bf16);

    __bf16* Qh = w;
    __bf16* Ql = split ? (w + TD) : nullptr;
    __bf16* Eb = split ? (w + 2 * TD) : (w + TD);

    conv_kernel<<<dim3((int)(TD / 4 / 256)), 256, 0, stream>>>(emb, Eb);
    if (split) {
        qproj_kernel<true><<<dim3(Tt / 64, Dd / 64), 256, 0, stream>>>(emb, Wq, bq, Qh, Ql);
        span_attn_kernel<true><<<dim3(Nn / 4), 256, 0, stream>>>(Eb, spans, Qh, Ql, out);
    } else {
        qproj_kernel<false><<<dim3(Tt / 64, Dd / 64), 256, 0, stream>>>(emb, Wq, bq, Qh, nullptr);
        span_attn_kernel<false><<<dim3(Nn / 4), 256, 0, stream>>>(Eb, spans, Qh, nullptr, out);
    }
}

// Round 4
// 296.350 us; speedup vs baseline: 2.0773x; 1.6049x over previous
//
#include <hip/hip_runtime.h>
#include <hip/hip_bf16.h>
#include <cstddef>
#include <cstdint>

constexpr int Tt = 8192;
constexpr int Dd = 768;
constexpr int Nn = 10000;
constexpr int Ww = 32;

typedef __bf16 bf16x8 __attribute__((ext_vector_type(8)));
typedef __bf16 bf16x4 __attribute__((ext_vector_type(4)));
typedef __bf16 bf16x2 __attribute__((ext_vector_type(2)));
typedef float f32x4 __attribute__((ext_vector_type(4)));

#define MFMA16(a, b, c) __builtin_amdgcn_mfma_f32_16x16x32_bf16((a), (b), (c), 0, 0, 0)

// ---------------------------------------------------------------------------
// fp32 -> bf16 hi (+ optional lo) converter.
// ---------------------------------------------------------------------------
template <bool LO>
__global__ __launch_bounds__(256) void conv_kernel(const float* __restrict__ src,
                                                   __bf16* __restrict__ h,
                                                   __bf16* __restrict__ l, int n4) {
    const int i = blockIdx.x * 256 + threadIdx.x;
    if (i >= n4) return;
    const float4 v = reinterpret_cast<const float4*>(src)[i];
    bf16x4 oh, ol;
    oh[0] = (__bf16)v.x; oh[1] = (__bf16)v.y; oh[2] = (__bf16)v.z; oh[3] = (__bf16)v.w;
    reinterpret_cast<bf16x4*>(h)[i] = oh;
    if (LO) {
        ol[0] = (__bf16)(v.x - (float)oh[0]);
        ol[1] = (__bf16)(v.y - (float)oh[1]);
        ol[2] = (__bf16)(v.z - (float)oh[2]);
        ol[3] = (__bf16)(v.w - (float)oh[3]);
        reinterpret_cast<bf16x4*>(l)[i] = ol;
    }
}

// ---------------------------------------------------------------------------
// Counting sort of span indices by start: zero -> hist -> scan -> scatter.
// Fully rebuilt every call; insensitive to workspace poison.
// ---------------------------------------------------------------------------
__global__ __launch_bounds__(256) void zero_kernel(int* __restrict__ p, int n) {
    const int i = blockIdx.x * 256 + threadIdx.x;
    if (i < n) p[i] = 0;
}

__global__ __launch_bounds__(256) void hist_kernel(const int* __restrict__ spans,
                                                   int* __restrict__ hist) {
    const int i = blockIdx.x * 256 + threadIdx.x;
    if (i < Nn) atomicAdd(&hist[spans[2 * i]], 1);
}

__global__ __launch_bounds__(256) void scan_kernel(int* __restrict__ hist) {
    __shared__ int part[256];
    const int t = threadIdx.x;
    int vals[32];
    int sum = 0;
#pragma unroll
    for (int i = 0; i < 32; ++i) { vals[i] = hist[t * 32 + i]; sum += vals[i]; }
    part[t] = sum;
    __syncthreads();
    for (int off = 1; off < 256; off <<= 1) {
        const int v = (t >= off) ? part[t - off] : 0;
        __syncthreads();
        part[t] += v;
        __syncthreads();
    }
    int run = (t == 0) ? 0 : part[t - 1];
#pragma unroll
    for (int i = 0; i < 32; ++i) { const int v = vals[i]; hist[t * 32 + i] = run; run += v; }
}

__global__ __launch_bounds__(256) void scatter_kernel(const int* __restrict__ spans,
                                                      int* __restrict__ offs,
                                                      int* __restrict__ perm) {
    const int i = blockIdx.x * 256 + threadIdx.x;
    if (i < Nn) {
        const int p = atomicAdd(&offs[spans[2 * i]], 1);
        perm[p] = i;
    }
}

// ---------------------------------------------------------------------------
// fp32 vector qproj (fallback tiers). Q = emb @ Wq^T + bq, bf16 hi/lo out.
// ---------------------------------------------------------------------------
template <bool SPLIT>
__global__ __launch_bounds__(256) void qproj_kernel(const float* __restrict__ emb,
                                                    const float* __restrict__ Wq,
                                                    const float* __restrict__ bq,
                                                    __bf16* __restrict__ Qh,
                                                    __bf16* __restrict__ Ql) {
    __shared__ float As[64][32];
    __shared__ float Bs[64][32];
    const int tid = threadIdx.x;
    const int tx = tid & 15;
    const int ty = tid >> 4;
    const int m0 = blockIdx.x * 64;
    const int n0 = blockIdx.y * 64;

    float acc[4][4] = {};

    for (int kc = 0; kc < Dd; kc += 32) {
#pragma unroll
        for (int i = 0; i < 2; ++i) {
            const int f   = tid + i * 256;
            const int row = f >> 3;
            const int c4  = f & 7;
            const int ph  = (c4 + (row >> 2)) & 7;
            *reinterpret_cast<float4*>(&As[row][ph * 4]) =
                *reinterpret_cast<const float4*>(&emb[(size_t)(m0 + row) * Dd + kc + c4 * 4]);
            *reinterpret_cast<float4*>(&Bs[row][ph * 4]) =
                *reinterpret_cast<const float4*>(&Wq[(size_t)(n0 + row) * Dd + kc + c4 * 4]);
        }
        __syncthreads();
#pragma unroll
        for (int d4 = 0; d4 < 8; ++d4) {
            float4 av[4], bv[4];
#pragma unroll
            for (int r = 0; r < 4; ++r)
                av[r] = *reinterpret_cast<const float4*>(&As[ty * 4 + r][((d4 + ty) & 7) * 4]);
#pragma unroll
            for (int c = 0; c < 4; ++c)
                bv[c] = *reinterpret_cast<const float4*>(&Bs[tx * 4 + c][((d4 + tx) & 7) * 4]);
#pragma unroll
            for (int r = 0; r < 4; ++r)
#pragma unroll
                for (int c = 0; c < 4; ++c) {
                    acc[r][c] += av[r].x * bv[c].x;
                    acc[r][c] += av[r].y * bv[c].y;
                    acc[r][c] += av[r].z * bv[c].z;
                    acc[r][c] += av[r].w * bv[c].w;
                }
        }
        __syncthreads();
    }
#pragma unroll
    for (int r = 0; r < 4; ++r) {
        bf16x4 oh, ol;
#pragma unroll
        for (int c = 0; c < 4; ++c) {
            const float v = acc[r][c] + bq[n0 + tx * 4 + c];
            const __bf16 h = (__bf16)v;
            oh[c] = h;
            if (SPLIT) ol[c] = (__bf16)(v - (float)h);
        }
        const size_t off = (size_t)(m0 + ty * 4 + r) * Dd + n0 + tx * 4;
        *reinterpret_cast<bf16x4*>(&Qh[off]) = oh;
        if (SPLIT) *reinterpret_cast<bf16x4*>(&Ql[off]) = ol;
    }
}

// ---------------------------------------------------------------------------
// MFMA qproj, SYNCHRONOUS staging (global->VGPR->ds_write_b128, no
// global_load_lds). Q = emb @ Wq^T + bq via 3-term bf16 split.
// 128x128 tile, 4 waves x 64x64, BK=32, XOR-swizzled LDS chunks.
// ---------------------------------------------------------------------------
__global__ __launch_bounds__(256) void qproj_mfma_kernel(const __bf16* __restrict__ Eh,
                                                         const __bf16* __restrict__ El,
                                                         const __bf16* __restrict__ Wh,
                                                         const __bf16* __restrict__ Wl,
                                                         const float* __restrict__ bq,
                                                         __bf16* __restrict__ Qh,
                                                         __bf16* __restrict__ Ql) {
    __shared__ __align__(16) __bf16 Ahs[128 * 32];
    __shared__ __align__(16) __bf16 Als[128 * 32];
    __shared__ __align__(16) __bf16 Bhs[128 * 32];
    __shared__ __align__(16) __bf16 Bls[128 * 32];

    const int tid  = threadIdx.x;
    const int wave = tid >> 6;
    const int lane = tid & 63;

    const int b   = blockIdx.x;       // 0..383
    const int xcd = b & 7;
    const int li  = b >> 3;           // 0..47
    const int mt  = xcd * 8 + li / 6; // 0..63
    const int nt  = li % 6;           // 0..5
    const int m0 = mt * 128;
    const int n0 = nt * 128;
    const int wm = (wave & 1) * 64;
    const int wn = (wave >> 1) * 64;
    const int fr = lane & 15;
    const int kg = lane >> 4;

    f32x4 acc[4][4] = {};

    for (int kc = 0; kc < Dd; kc += 32) {
        // Stage to registers first (synchronous vector loads).
        bf16x8 rah[2], ral[2], rbh[2], rbl[2];
        int slotArr[2];
#pragma unroll
        for (int ch = 0; ch < 2; ++ch) {
            const int slot = ch * 256 + tid;
            slotArr[ch] = slot;
            const int row  = slot >> 2;
            const int c4   = slot & 3;
            const int gc   = (c4 ^ (row & 3)) * 8;  // XOR swizzle
            const size_t ga = (size_t)(m0 + row) * Dd + kc + gc;
            const size_t gb = (size_t)(n0 + row) * Dd + kc + gc;
            rah[ch] = *reinterpret_cast<const bf16x8*>(&Eh[ga]);
            ral[ch] = *reinterpret_cast<const bf16x8*>(&El[ga]);
            rbh[ch] = *reinterpret_cast<const bf16x8*>(&Wh[gb]);
            rbl[ch] = *reinterpret_cast<const bf16x8*>(&Wl[gb]);
        }
        __syncthreads();  // previous iteration's LDS reads complete
#pragma unroll
        for (int ch = 0; ch < 2; ++ch) {
            const int slot = slotArr[ch];
            *reinterpret_cast<bf16x8*>(&Ahs[slot * 8]) = rah[ch];
            *reinterpret_cast<bf16x8*>(&Als[slot * 8]) = ral[ch];
            *reinterpret_cast<bf16x8*>(&Bhs[slot * 8]) = rbh[ch];
            *reinterpret_cast<bf16x8*>(&Bls[slot * 8]) = rbl[ch];
        }
        __syncthreads();  // LDS writes visible to all waves

        bf16x8 ah[4], al[4], bh[4], bl[4];
#pragma unroll
        for (int r = 0; r < 4; ++r) {
            const int R = wm + r * 16 + fr;
            const int p = (kg ^ (R & 3)) * 8;
            ah[r] = *reinterpret_cast<const bf16x8*>(&Ahs[R * 32 + p]);
            al[r] = *reinterpret_cast<const bf16x8*>(&Als[R * 32 + p]);
        }
#pragma unroll
        for (int c = 0; c < 4; ++c) {
            const int R = wn + c * 16 + fr;
            const int p = (kg ^ (R & 3)) * 8;
            bh[c] = *reinterpret_cast<const bf16x8*>(&Bhs[R * 32 + p]);
            bl[c] = *reinterpret_cast<const bf16x8*>(&Bls[R * 32 + p]);
        }
#pragma unroll
        for (int r = 0; r < 4; ++r)
#pragma unroll
            for (int c = 0; c < 4; ++c) {
                acc[r][c] = MFMA16(ah[r], bh[c], acc[r][c]);
                acc[r][c] = MFMA16(al[r], bh[c], acc[r][c]);
                acc[r][c] = MFMA16(ah[r], bl[c], acc[r][c]);
            }
    }

    // Epilogue: C/D layout col=lane&15, row=(lane>>4)*4+reg.
#pragma unroll
    for (int c = 0; c < 4; ++c) {
        const int ocol = n0 + wn + c * 16 + fr;
        const float bqv = bq[ocol];
#pragma unroll
        for (int r = 0; r < 4; ++r)
#pragma unroll
            for (int j = 0; j < 4; ++j) {
                const int orow = m0 + wm + r * 16 + kg * 4 + j;
                const float v  = acc[r][c][j] + bqv;
                const __bf16 h = (__bf16)v;
                Qh[(size_t)orow * Dd + ocol] = h;
                Ql[(size_t)orow * Dd + ocol] = (__bf16)(v - (float)h);
            }
    }
}

// ---------------------------------------------------------------------------
// Span attention: one wave per span. Optional sorted order + XCD swizzle.
// ---------------------------------------------------------------------------
template <bool SPLIT, bool SORTED>
__global__ __launch_bounds__(256) void span_attn_kernel(const __bf16* __restrict__ Eb,
                                                        const int* __restrict__ spans,
                                                        const __bf16* __restrict__ Qh,
                                                        const __bf16* __restrict__ Ql,
                                                        const int* __restrict__ perm,
                                                        float* __restrict__ out) {
    __shared__ float Ss[4][32 * 33];
    __shared__ float Cs[4][32];

    const int wave = threadIdx.x >> 6;
    const int lane = threadIdx.x & 63;

    int s;
    bool active;
    if (SORTED) {
        // 2504 blocks; bp = (b&7)*313 + (b>>3): each XCD gets a contiguous chunk.
        const int b    = blockIdx.x;
        const int bp   = (b & 7) * 313 + (b >> 3);
        const int slot = bp * 4 + wave;
        active = slot < Nn;
        s = active ? perm[slot] : 0;
        if ((unsigned)s >= (unsigned)Nn) s = 0;  // paranoia vs poisoned perm
    } else {
        s = blockIdx.x * 4 + wave;
        active = true;
    }

    const int start = spans[2 * s];
    const int L     = spans[2 * s + 1] - start + 1;  // 1..32
    const bool big  = L > 16;

    const int row = lane & 15;
    const int kq  = lane >> 4;

    const size_t rbase = (size_t)(start + row) * Dd + kq * 8;
    const __bf16* qh0 = Qh + rbase;
    const __bf16* eb0 = Eb + rbase;
    const __bf16* ql0 = SPLIT ? (Ql + rbase) : nullptr;

    f32x4 acc00 = {0.f, 0.f, 0.f, 0.f};
    f32x4 acc01 = {0.f, 0.f, 0.f, 0.f};
    f32x4 acc10 = {0.f, 0.f, 0.f, 0.f};
    f32x4 acc11 = {0.f, 0.f, 0.f, 0.f};

    for (int k0 = 0; k0 < Dd; k0 += 32) {
        const bf16x8 a0 = *reinterpret_cast<const bf16x8*>(qh0 + k0);
        const bf16x8 b0 = *reinterpret_cast<const bf16x8*>(eb0 + k0);
        acc00 = MFMA16(a0, b0, acc00);
        bf16x8 al0;
        if (SPLIT) {
            al0 = *reinterpret_cast<const bf16x8*>(ql0 + k0);
            acc00 = MFMA16(al0, b0, acc00);
        }
        if (big) {
            const bf16x8 a1 = *reinterpret_cast<const bf16x8*>(qh0 + 16 * Dd + k0);
            const bf16x8 b1 = *reinterpret_cast<const bf16x8*>(eb0 + 16 * Dd + k0);
            acc01 = MFMA16(a0, b1, acc01);
            acc10 = MFMA16(a1, b0, acc10);
            acc11 = MFMA16(a1, b1, acc11);
            if (SPLIT) {
                const bf16x8 al1 = *reinterpret_cast<const bf16x8*>(ql0 + 16 * Dd + k0);
                acc01 = MFMA16(al0, b1, acc01);
                acc10 = MFMA16(al1, b0, acc10);
                acc11 = MFMA16(al1, b1, acc11);
            }
        }
    }

    float* S_ = Ss[wave];
#pragma unroll
    for (int r = 0; r < 4; ++r) {
        const int q = kq * 4 + r;
        S_[q * 33 + row] = acc00[r];
        if (big) {
            S_[q * 33 + 16 + row]        = acc01[r];
            S_[(16 + q) * 33 + row]      = acc10[r];
            S_[(16 + q) * 33 + 16 + row] = acc11[r];
        }
    }
    __syncthreads();

    if (lane < 32 && lane < L) {
        float m = -1e30f;
        for (int k = 0; k < L; ++k) m = fmaxf(m, S_[lane * 33 + k]);
        float sum = 0.f;
        for (int k = 0; k < L; ++k) {
            const float e = __expf(S_[lane * 33 + k] - m);
            S_[lane * 33 + k] = e;
            sum += e;
        }
        const float inv = 1.f / sum;
        for (int k = 0; k < L; ++k) S_[lane * 33 + k] *= inv;
    }
    __syncthreads();

    if (lane < 32) {
        float c = 0.f;
        if (lane < L)
            for (int q = 0; q < L; ++q) c += S_[q * 33 + lane];
        Cs[wave][lane] = c;
    }
    __syncthreads();

    if (active) {
#pragma unroll
        for (int i = 0; i < Dd / 128; ++i) {
            const int d = i * 128 + lane * 2;
            float vx = 0.f, vy = 0.f;
            for (int k = 0; k < L; ++k) {
                const float c = Cs[wave][k];
                const bf16x2 e = *reinterpret_cast<const bf16x2*>(&Eb[(size_t)(start + k) * Dd + d]);
                vx += c * (float)e[0];
                vy += c * (float)e[1];
            }
            float2 o; o.x = vx; o.y = vy;
            *reinterpret_cast<float2*>(&out[(size_t)s * Dd + d]) = o;
        }
    }
}

// ---------------------------------------------------------------------------
extern "C" void kernel_launch(void* const* d_in, const int* in_sizes, int n_in,
                              void* d_out, int out_size, void* d_ws, size_t ws_size,
                              hipStream_t stream) {
    const float* emb   = (const float*)d_in[0];
    const int*   spans = (const int*)d_in[1];
    const float* Wq    = (const float*)d_in[2];
    const float* bq    = (const float*)d_in[3];
    float*       out   = (float*)d_out;

    const size_t TD = (size_t)Tt * Dd;
    const size_t DD = (size_t)Dd * Dd;
    const int nInts = 8192 + 10016;
    const size_t intBytes = (size_t)nInts * sizeof(int);
    auto align16 = [](size_t x) { return (x + 15) & ~(size_t)15; };

    const size_t needA = align16((4 * TD + 2 * DD) * 2) + intBytes;
    const size_t needB = align16(3 * TD * 2) + intBytes;
    const size_t needC = 3 * TD * 2;

    __bf16* w = (__bf16*)d_ws;

    if (ws_size >= needA) {
        // Full path: MFMA qproj (sync staging) + sorted spans.
        __bf16* Qh = w;
        __bf16* Ql = w + TD;
        __bf16* Eh = w + 2 * TD;
        __bf16* El = w + 3 * TD;
        __bf16* Wh = w + 4 * TD;
        __bf16* Wl = Wh + DD;
        int* hist = (int*)((char*)d_ws + align16((4 * TD + 2 * DD) * 2));
        int* perm = hist + 8192;

        conv_kernel<true><<<(int)(TD / 4 + 255) / 256, 256, 0, stream>>>(emb, Eh, El, (int)(TD / 4));
        conv_kernel<true><<<(int)(DD / 4 + 255) / 256, 256, 0, stream>>>(Wq, Wh, Wl, (int)(DD / 4));
        zero_kernel<<<(nInts + 255) / 256, 256, 0, stream>>>(hist, nInts);
        hist_kernel<<<40, 256, 0, stream>>>(spans, hist);
        scan_kernel<<<1, 256, 0, stream>>>(hist);
        scatter_kernel<<<40, 256, 0, stream>>>(spans, hist, perm);
        qproj_mfma_kernel<<<384, 256, 0, stream>>>(Eh, El, Wh, Wl, bq, Qh, Ql);
        span_attn_kernel<true, true><<<2504, 256, 0, stream>>>(Eh, spans, Qh, Ql, perm, out);
    } else if (ws_size >= needB) {
        // fp32 qproj + sorted spans.
        __bf16* Qh = w;
        __bf16* Ql = w + TD;
        __bf16* Eh = w + 2 * TD;
        int* hist = (int*)((char*)d_ws + align16(3 * TD * 2));
        int* perm = hist + 8192;

        conv_kernel<false><<<(int)(TD / 4 + 255) / 256, 256, 0, stream>>>(emb, Eh, nullptr, (int)(TD / 4));
        zero_kernel<<<(nInts + 255) / 256, 256, 0, stream>>>(hist, nInts);
        hist_kernel<<<40, 256, 0, stream>>>(spans, hist);
        scan_kernel<<<1, 256, 0, stream>>>(hist);
        scatter_kernel<<<40, 256, 0, stream>>>(spans, hist, perm);
        qproj_kernel<true><<<dim3(Tt / 64, Dd / 64), 256, 0, stream>>>(emb, Wq, bq, Qh, Ql);
        span_attn_kernel<true, true><<<2504, 256, 0, stream>>>(Eh, spans, Qh, Ql, perm, out);
    } else if (ws_size >= needC) {
        // Exact round-2 behavior (proven): split, no sort.
        __bf16* Qh = w;
        __bf16* Ql = w + TD;
        __bf16* Eh = w + 2 * TD;
        conv_kernel<false><<<(int)(TD / 4 + 255) / 256, 256, 0, stream>>>(emb, Eh, nullptr, (int)(TD / 4));
        qproj_kernel<true><<<dim3(Tt / 64, Dd / 64), 256, 0, stream>>>(emb, Wq, bq, Qh, Ql);
        span_attn_kernel<true, false><<<2500, 256, 0, stream>>>(Eh, spans, Qh, Ql, nullptr, out);
    } else {
        // Minimal: non-split, no sort.
        __bf16* Qh = w;
        __bf16* Eh = w + TD;
        conv_kernel<false><<<(int)(TD / 4 + 255) / 256, 256, 0, stream>>>(emb, Eh, nullptr, (int)(TD / 4));
        qproj_kernel<false><<<dim3(Tt / 64, Dd / 64), 256, 0, stream>>>(emb, Wq, bq, Qh, nullptr);
        span_attn_kernel<false, false><<<2500, 256, 0, stream>>>(Eh, spans, Qh, nullptr, nullptr, out);
    }
}

// Round 5
// 296.067 us; speedup vs baseline: 2.0793x; 1.0010x over previous
//
#include <hip/hip_runtime.h>
#include <hip/hip_bf16.h>
#include <cstddef>
#include <cstdint>

constexpr int Tt = 8192;
constexpr int Dd = 768;
constexpr int Nn = 10000;
constexpr int Ww = 32;

typedef __bf16 bf16x8 __attribute__((ext_vector_type(8)));
typedef __bf16 bf16x4 __attribute__((ext_vector_type(4)));
typedef __bf16 bf16x2 __attribute__((ext_vector_type(2)));
typedef float f32x4 __attribute__((ext_vector_type(4)));

#define MFMA16(a, b, c) __builtin_amdgcn_mfma_f32_16x16x32_bf16((a), (b), (c), 0, 0, 0)

// ---------------------------------------------------------------------------
// fp32 -> bf16 hi (+ optional lo) converter.
// ---------------------------------------------------------------------------
template <bool LO>
__global__ __launch_bounds__(256) void conv_kernel(const float* __restrict__ src,
                                                   __bf16* __restrict__ h,
                                                   __bf16* __restrict__ l, int n4) {
    const int i = blockIdx.x * 256 + threadIdx.x;
    if (i >= n4) return;
    const float4 v = reinterpret_cast<const float4*>(src)[i];
    bf16x4 oh, ol;
    oh[0] = (__bf16)v.x; oh[1] = (__bf16)v.y; oh[2] = (__bf16)v.z; oh[3] = (__bf16)v.w;
    reinterpret_cast<bf16x4*>(h)[i] = oh;
    if (LO) {
        ol[0] = (__bf16)(v.x - (float)oh[0]);
        ol[1] = (__bf16)(v.y - (float)oh[1]);
        ol[2] = (__bf16)(v.z - (float)oh[2]);
        ol[3] = (__bf16)(v.w - (float)oh[3]);
        reinterpret_cast<bf16x4*>(l)[i] = ol;
    }
}

// ---------------------------------------------------------------------------
// Counting sort of span indices by start. Rebuilt fully every call.
// ---------------------------------------------------------------------------
__global__ __launch_bounds__(256) void zero_kernel(int* __restrict__ p, int n) {
    const int i = blockIdx.x * 256 + threadIdx.x;
    if (i < n) p[i] = 0;
}

__global__ __launch_bounds__(256) void hist_kernel(const int* __restrict__ spans,
                                                   int* __restrict__ hist) {
    const int i = blockIdx.x * 256 + threadIdx.x;
    if (i < Nn) atomicAdd(&hist[spans[2 * i]], 1);
}

__global__ __launch_bounds__(256) void scan_kernel(int* __restrict__ hist) {
    __shared__ int part[256];
    const int t = threadIdx.x;
    int vals[32];
    int sum = 0;
#pragma unroll
    for (int i = 0; i < 32; ++i) { vals[i] = hist[t * 32 + i]; sum += vals[i]; }
    part[t] = sum;
    __syncthreads();
    for (int off = 1; off < 256; off <<= 1) {
        const int v = (t >= off) ? part[t - off] : 0;
        __syncthreads();
        part[t] += v;
        __syncthreads();
    }
    int run = (t == 0) ? 0 : part[t - 1];
#pragma unroll
    for (int i = 0; i < 32; ++i) { const int v = vals[i]; hist[t * 32 + i] = run; run += v; }
}

__global__ __launch_bounds__(256) void scatter_kernel(const int* __restrict__ spans,
                                                      int* __restrict__ offs,
                                                      int* __restrict__ perm) {
    const int i = blockIdx.x * 256 + threadIdx.x;
    if (i < Nn) {
        const int p = atomicAdd(&offs[spans[2 * i]], 1);
        perm[p] = i;
    }
}

// ---------------------------------------------------------------------------
// fp32 vector qproj (deep fallback). Q = emb @ Wq^T + bq, bf16 hi/lo out.
// ---------------------------------------------------------------------------
template <bool SPLIT>
__global__ __launch_bounds__(256) void qproj_kernel(const float* __restrict__ emb,
                                                    const float* __restrict__ Wq,
                                                    const float* __restrict__ bq,
                                                    __bf16* __restrict__ Qh,
                                                    __bf16* __restrict__ Ql) {
    __shared__ float As[64][32];
    __shared__ float Bs[64][32];
    const int tid = threadIdx.x;
    const int tx = tid & 15;
    const int ty = tid >> 4;
    const int m0 = blockIdx.x * 64;
    const int n0 = blockIdx.y * 64;

    float acc[4][4] = {};

    for (int kc = 0; kc < Dd; kc += 32) {
#pragma unroll
        for (int i = 0; i < 2; ++i) {
            const int f   = tid + i * 256;
            const int row = f >> 3;
            const int c4  = f & 7;
            const int ph  = (c4 + (row >> 2)) & 7;
            *reinterpret_cast<float4*>(&As[row][ph * 4]) =
                *reinterpret_cast<const float4*>(&emb[(size_t)(m0 + row) * Dd + kc + c4 * 4]);
            *reinterpret_cast<float4*>(&Bs[row][ph * 4]) =
                *reinterpret_cast<const float4*>(&Wq[(size_t)(n0 + row) * Dd + kc + c4 * 4]);
        }
        __syncthreads();
#pragma unroll
        for (int d4 = 0; d4 < 8; ++d4) {
            float4 av[4], bv[4];
#pragma unroll
            for (int r = 0; r < 4; ++r)
                av[r] = *reinterpret_cast<const float4*>(&As[ty * 4 + r][((d4 + ty) & 7) * 4]);
#pragma unroll
            for (int c = 0; c < 4; ++c)
                bv[c] = *reinterpret_cast<const float4*>(&Bs[tx * 4 + c][((d4 + tx) & 7) * 4]);
#pragma unroll
            for (int r = 0; r < 4; ++r)
#pragma unroll
                for (int c = 0; c < 4; ++c) {
                    acc[r][c] += av[r].x * bv[c].x;
                    acc[r][c] += av[r].y * bv[c].y;
                    acc[r][c] += av[r].z * bv[c].z;
                    acc[r][c] += av[r].w * bv[c].w;
                }
        }
        __syncthreads();
    }
#pragma unroll
    for (int r = 0; r < 4; ++r) {
        bf16x4 oh, ol;
#pragma unroll
        for (int c = 0; c < 4; ++c) {
            const float v = acc[r][c] + bq[n0 + tx * 4 + c];
            const __bf16 h = (__bf16)v;
            oh[c] = h;
            if (SPLIT) ol[c] = (__bf16)(v - (float)h);
        }
        const size_t off = (size_t)(m0 + ty * 4 + r) * Dd + n0 + tx * 4;
        *reinterpret_cast<bf16x4*>(&Qh[off]) = oh;
        if (SPLIT) *reinterpret_cast<bf16x4*>(&Ql[off]) = ol;
    }
}

// ---------------------------------------------------------------------------
// MFMA qproj (round-4 proven, sync staging). Fallback when split-K ws lacks.
// ---------------------------------------------------------------------------
__global__ __launch_bounds__(256) void qproj_mfma_kernel(const __bf16* __restrict__ Eh,
                                                         const __bf16* __restrict__ El,
                                                         const __bf16* __restrict__ Wh,
                                                         const __bf16* __restrict__ Wl,
                                                         const float* __restrict__ bq,
                                                         __bf16* __restrict__ Qh,
                                                         __bf16* __restrict__ Ql) {
    __shared__ __align__(16) __bf16 Ahs[128 * 32];
    __shared__ __align__(16) __bf16 Als[128 * 32];
    __shared__ __align__(16) __bf16 Bhs[128 * 32];
    __shared__ __align__(16) __bf16 Bls[128 * 32];

    const int tid  = threadIdx.x;
    const int wave = tid >> 6;
    const int lane = tid & 63;

    const int b   = blockIdx.x;
    const int xcd = b & 7;
    const int li  = b >> 3;
    const int mt  = xcd * 8 + li / 6;
    const int nt  = li % 6;
    const int m0 = mt * 128;
    const int n0 = nt * 128;
    const int wm = (wave & 1) * 64;
    const int wn = (wave >> 1) * 64;
    const int fr = lane & 15;
    const int kg = lane >> 4;

    f32x4 acc[4][4] = {};

    for (int kc = 0; kc < Dd; kc += 32) {
        bf16x8 rah[2], ral[2], rbh[2], rbl[2];
        int slotArr[2];
#pragma unroll
        for (int ch = 0; ch < 2; ++ch) {
            const int slot = ch * 256 + tid;
            slotArr[ch] = slot;
            const int row  = slot >> 2;
            const int c4   = slot & 3;
            const int gc   = (c4 ^ (row & 3)) * 8;
            const size_t ga = (size_t)(m0 + row) * Dd + kc + gc;
            const size_t gb = (size_t)(n0 + row) * Dd + kc + gc;
            rah[ch] = *reinterpret_cast<const bf16x8*>(&Eh[ga]);
            ral[ch] = *reinterpret_cast<const bf16x8*>(&El[ga]);
            rbh[ch] = *reinterpret_cast<const bf16x8*>(&Wh[gb]);
            rbl[ch] = *reinterpret_cast<const bf16x8*>(&Wl[gb]);
        }
        __syncthreads();
#pragma unroll
        for (int ch = 0; ch < 2; ++ch) {
            const int slot = slotArr[ch];
            *reinterpret_cast<bf16x8*>(&Ahs[slot * 8]) = rah[ch];
            *reinterpret_cast<bf16x8*>(&Als[slot * 8]) = ral[ch];
            *reinterpret_cast<bf16x8*>(&Bhs[slot * 8]) = rbh[ch];
            *reinterpret_cast<bf16x8*>(&Bls[slot * 8]) = rbl[ch];
        }
        __syncthreads();

        bf16x8 ah[4], al[4], bh[4], bl[4];
#pragma unroll
        for (int r = 0; r < 4; ++r) {
            const int R = wm + r * 16 + fr;
            const int p = (kg ^ (R & 3)) * 8;
            ah[r] = *reinterpret_cast<const bf16x8*>(&Ahs[R * 32 + p]);
            al[r] = *reinterpret_cast<const bf16x8*>(&Als[R * 32 + p]);
        }
#pragma unroll
        for (int c = 0; c < 4; ++c) {
            const int R = wn + c * 16 + fr;
            const int p = (kg ^ (R & 3)) * 8;
            bh[c] = *reinterpret_cast<const bf16x8*>(&Bhs[R * 32 + p]);
            bl[c] = *reinterpret_cast<const bf16x8*>(&Bls[R * 32 + p]);
        }
#pragma unroll
        for (int r = 0; r < 4; ++r)
#pragma unroll
            for (int c = 0; c < 4; ++c) {
                acc[r][c] = MFMA16(ah[r], bh[c], acc[r][c]);
                acc[r][c] = MFMA16(al[r], bh[c], acc[r][c]);
                acc[r][c] = MFMA16(ah[r], bl[c], acc[r][c]);
            }
    }

#pragma unroll
    for (int c = 0; c < 4; ++c) {
        const int ocol = n0 + wn + c * 16 + fr;
        const float bqv = bq[ocol];
#pragma unroll
        for (int r = 0; r < 4; ++r)
#pragma unroll
            for (int j = 0; j < 4; ++j) {
                const int orow = m0 + wm + r * 16 + kg * 4 + j;
                const float v  = acc[r][c][j] + bqv;
                const __bf16 h = (__bf16)v;
                Qh[(size_t)orow * Dd + ocol] = h;
                Ql[(size_t)orow * Dd + ocol] = (__bf16)(v - (float)h);
            }
    }
}

// ---------------------------------------------------------------------------
// Split-K=2 MFMA qproj: 768 blocks (3/CU even), each does half of K into an
// fp32 partial buffer P[half]. Deterministic (disjoint buffers).
// ---------------------------------------------------------------------------
__global__ __launch_bounds__(256) void qproj_mfma_splitk_kernel(const __bf16* __restrict__ Eh,
                                                                const __bf16* __restrict__ El,
                                                                const __bf16* __restrict__ Wh,
                                                                const __bf16* __restrict__ Wl,
                                                                float* __restrict__ P) {
    __shared__ __align__(16) __bf16 Ahs[128 * 32];
    __shared__ __align__(16) __bf16 Als[128 * 32];
    __shared__ __align__(16) __bf16 Bhs[128 * 32];
    __shared__ __align__(16) __bf16 Bls[128 * 32];

    const int tid  = threadIdx.x;
    const int wave = tid >> 6;
    const int lane = tid & 63;

    // b in [0,768): xcd = b&7; li = b>>3 in [0,96): half|mtl|nt grouped so the
    // 6 n-tiles of one (mt, half) share an XCD (A-row L2 reuse).
    const int b    = blockIdx.x;
    const int xcd  = b & 7;
    const int li   = b >> 3;
    const int half = li / 48;
    const int r2   = li % 48;
    const int mt   = xcd * 8 + r2 / 6;
    const int nt   = r2 % 6;
    const int m0 = mt * 128;
    const int n0 = nt * 128;
    const int wm = (wave & 1) * 64;
    const int wn = (wave >> 1) * 64;
    const int fr = lane & 15;
    const int kg = lane >> 4;
    const int kbeg = half * (Dd / 2);

    f32x4 acc[4][4] = {};

    for (int kk = 0; kk < Dd / 2; kk += 32) {
        const int kc = kbeg + kk;
        bf16x8 rah[2], ral[2], rbh[2], rbl[2];
        int slotArr[2];
#pragma unroll
        for (int ch = 0; ch < 2; ++ch) {
            const int slot = ch * 256 + tid;
            slotArr[ch] = slot;
            const int row  = slot >> 2;
            const int c4   = slot & 3;
            const int gc   = (c4 ^ (row & 3)) * 8;
            const size_t ga = (size_t)(m0 + row) * Dd + kc + gc;
            const size_t gb = (size_t)(n0 + row) * Dd + kc + gc;
            rah[ch] = *reinterpret_cast<const bf16x8*>(&Eh[ga]);
            ral[ch] = *reinterpret_cast<const bf16x8*>(&El[ga]);
            rbh[ch] = *reinterpret_cast<const bf16x8*>(&Wh[gb]);
            rbl[ch] = *reinterpret_cast<const bf16x8*>(&Wl[gb]);
        }
        __syncthreads();
#pragma unroll
        for (int ch = 0; ch < 2; ++ch) {
            const int slot = slotArr[ch];
            *reinterpret_cast<bf16x8*>(&Ahs[slot * 8]) = rah[ch];
            *reinterpret_cast<bf16x8*>(&Als[slot * 8]) = ral[ch];
            *reinterpret_cast<bf16x8*>(&Bhs[slot * 8]) = rbh[ch];
            *reinterpret_cast<bf16x8*>(&Bls[slot * 8]) = rbl[ch];
        }
        __syncthreads();

        bf16x8 ah[4], al[4], bh[4], bl[4];
#pragma unroll
        for (int r = 0; r < 4; ++r) {
            const int R = wm + r * 16 + fr;
            const int p = (kg ^ (R & 3)) * 8;
            ah[r] = *reinterpret_cast<const bf16x8*>(&Ahs[R * 32 + p]);
            al[r] = *reinterpret_cast<const bf16x8*>(&Als[R * 32 + p]);
        }
#pragma unroll
        for (int c = 0; c < 4; ++c) {
            const int R = wn + c * 16 + fr;
            const int p = (kg ^ (R & 3)) * 8;
            bh[c] = *reinterpret_cast<const bf16x8*>(&Bhs[R * 32 + p]);
            bl[c] = *reinterpret_cast<const bf16x8*>(&Bls[R * 32 + p]);
        }
#pragma unroll
        for (int r = 0; r < 4; ++r)
#pragma unroll
            for (int c = 0; c < 4; ++c) {
                acc[r][c] = MFMA16(ah[r], bh[c], acc[r][c]);
                acc[r][c] = MFMA16(al[r], bh[c], acc[r][c]);
                acc[r][c] = MFMA16(ah[r], bl[c], acc[r][c]);
            }
    }

    float* Po = P + (size_t)half * Tt * Dd;
#pragma unroll
    for (int c = 0; c < 4; ++c) {
        const int ocol = n0 + wn + c * 16 + fr;
#pragma unroll
        for (int r = 0; r < 4; ++r)
#pragma unroll
            for (int j = 0; j < 4; ++j) {
                const int orow = m0 + wm + r * 16 + kg * 4 + j;
                Po[(size_t)orow * Dd + ocol] = acc[r][c][j];
            }
    }
}

__global__ __launch_bounds__(256) void qcombine_kernel(const float* __restrict__ P,
                                                       const float* __restrict__ bq,
                                                       __bf16* __restrict__ Qh,
                                                       __bf16* __restrict__ Ql) {
    const int i = blockIdx.x * 256 + threadIdx.x;  // TD/4 threads exactly
    const float4 p0 = reinterpret_cast<const float4*>(P)[i];
    const float4 p1 = reinterpret_cast<const float4*>(P + (size_t)Tt * Dd)[i];
    const int col = (i * 4) % Dd;
    const float4 bv = *reinterpret_cast<const float4*>(&bq[col]);
    float v[4] = {p0.x + p1.x + bv.x, p0.y + p1.y + bv.y,
                  p0.z + p1.z + bv.z, p0.w + p1.w + bv.w};
    bf16x4 oh, ol;
#pragma unroll
    for (int j = 0; j < 4; ++j) {
        oh[j] = (__bf16)v[j];
        ol[j] = (__bf16)(v[j] - (float)oh[j]);
    }
    reinterpret_cast<bf16x4*>(Qh)[i] = oh;
    reinterpret_cast<bf16x4*>(Ql)[i] = ol;
}

// ---------------------------------------------------------------------------
// Span attention v2: one wave per span, ZERO LDS, ZERO barriers.
// Scores: batched direct-from-global MFMA fragments (12 loads in flight).
// Softmax + column sums fully in registers via __shfl_xor butterflies.
// C/D layout: k = lane&15 (col), q = (lane>>4)*4 + reg (row).
// Output: sum_k c_k * E[start+k], k unrolled x4, c_k broadcast via __shfl.
// ---------------------------------------------------------------------------
template <bool SPLIT, bool SORTED>
__global__ __launch_bounds__(256) void span_attn_kernel(const __bf16* __restrict__ Eb,
                                                        const int* __restrict__ spans,
                                                        const __bf16* __restrict__ Qh,
                                                        const __bf16* __restrict__ Ql,
                                                        const int* __restrict__ perm,
                                                        float* __restrict__ out) {
    const int wave = threadIdx.x >> 6;
    const int lane = threadIdx.x & 63;

    int s;
    bool active;
    if (SORTED) {
        const int b    = blockIdx.x;
        const int bp   = (b & 7) * 313 + (b >> 3);
        const int slot = bp * 4 + wave;
        active = slot < Nn;
        int sv = active ? perm[slot] : 0;
        if ((unsigned)sv >= (unsigned)Nn) sv = 0;
        s = sv;
    } else {
        s = blockIdx.x * 4 + wave;
        active = true;
    }

    const int start = spans[2 * s];
    const int L     = spans[2 * s + 1] - start + 1;  // 1..32
    const bool big  = L > 16;

    const int row = lane & 15;  // A-frag m; C-col k
    const int kq  = lane >> 4;

    const size_t rbase = (size_t)(start + row) * Dd + kq * 8;
    const __bf16* qh0 = Qh + rbase;
    const __bf16* eb0 = Eb + rbase;
    const __bf16* ql0 = SPLIT ? (Ql + rbase) : nullptr;

    f32x4 acc00 = {0.f, 0.f, 0.f, 0.f};
    f32x4 acc01 = {0.f, 0.f, 0.f, 0.f};
    f32x4 acc10 = {0.f, 0.f, 0.f, 0.f};
    f32x4 acc11 = {0.f, 0.f, 0.f, 0.f};

    if (!big) {
        for (int kc = 0; kc < Dd; kc += 128) {
            bf16x8 A[4], B[4], AL[4];
#pragma unroll
            for (int j = 0; j < 4; ++j) {
                const int o = kc + j * 32;
                A[j] = *reinterpret_cast<const bf16x8*>(qh0 + o);
                B[j] = *reinterpret_cast<const bf16x8*>(eb0 + o);
                if (SPLIT) AL[j] = *reinterpret_cast<const bf16x8*>(ql0 + o);
            }
#pragma unroll
            for (int j = 0; j < 4; ++j) {
                acc00 = MFMA16(A[j], B[j], acc00);
                if (SPLIT) acc00 = MFMA16(AL[j], B[j], acc00);
            }
        }
    } else {
        for (int kc = 0; kc < Dd; kc += 64) {
            bf16x8 A0[2], A1[2], B0[2], B1[2], AL0[2], AL1[2];
#pragma unroll
            for (int j = 0; j < 2; ++j) {
                const int o = kc + j * 32;
                A0[j] = *reinterpret_cast<const bf16x8*>(qh0 + o);
                A1[j] = *reinterpret_cast<const bf16x8*>(qh0 + 16 * Dd + o);
                B0[j] = *reinterpret_cast<const bf16x8*>(eb0 + o);
                B1[j] = *reinterpret_cast<const bf16x8*>(eb0 + 16 * Dd + o);
                if (SPLIT) {
                    AL0[j] = *reinterpret_cast<const bf16x8*>(ql0 + o);
                    AL1[j] = *reinterpret_cast<const bf16x8*>(ql0 + 16 * Dd + o);
                }
            }
#pragma unroll
            for (int j = 0; j < 2; ++j) {
                acc00 = MFMA16(A0[j], B0[j], acc00);
                acc01 = MFMA16(A0[j], B1[j], acc01);
                acc10 = MFMA16(A1[j], B0[j], acc10);
                acc11 = MFMA16(A1[j], B1[j], acc11);
                if (SPLIT) {
                    acc00 = MFMA16(AL0[j], B0[j], acc00);
                    acc01 = MFMA16(AL0[j], B1[j], acc01);
                    acc10 = MFMA16(AL1[j], B0[j], acc10);
                    acc11 = MFMA16(AL1[j], B1[j], acc11);
                }
            }
        }
    }

    // ---- In-register softmax + column sums (no LDS, no barriers) ----
    const float NEG = -1e30f;
    const bool kv0 = row < L;         // col k = row valid
    const bool kv1 = (16 + row) < L;  // col k = 16+row valid
    float cA, cB;                     // c_k for k=row and k=16+row
    {
        float w00[4], w01[4], w10[4], w11[4];
#pragma unroll
        for (int r = 0; r < 4; ++r) {
            // low rows q = kq*4 + r
            float m = kv0 ? acc00[r] : NEG;
            if (big) m = fmaxf(m, kv1 ? acc01[r] : NEG);
#pragma unroll
            for (int st = 1; st <= 8; st <<= 1) m = fmaxf(m, __shfl_xor(m, st));
            const float e0 = kv0 ? __expf(acc00[r] - m) : 0.f;
            const float e1 = (big && kv1) ? __expf(acc01[r] - m) : 0.f;
            float sum = e0 + e1;
#pragma unroll
            for (int st = 1; st <= 8; st <<= 1) sum += __shfl_xor(sum, st);
            const float inv = 1.f / sum;
            const bool qv = (kq * 4 + r) < L;
            w00[r] = qv ? e0 * inv : 0.f;
            w01[r] = qv ? e1 * inv : 0.f;
            if (big) {
                // high rows q = 16 + kq*4 + r
                float mh = kv0 ? acc10[r] : NEG;
                mh = fmaxf(mh, kv1 ? acc11[r] : NEG);
#pragma unroll
                for (int st = 1; st <= 8; st <<= 1) mh = fmaxf(mh, __shfl_xor(mh, st));
                const float f0 = kv0 ? __expf(acc10[r] - mh) : 0.f;
                const float f1 = kv1 ? __expf(acc11[r] - mh) : 0.f;
                float sh = f0 + f1;
#pragma unroll
                for (int st = 1; st <= 8; st <<= 1) sh += __shfl_xor(sh, st);
                const float invh = 1.f / sh;
                const bool qvh = (16 + kq * 4 + r) < L;
                w10[r] = qvh ? f0 * invh : 0.f;
                w11[r] = qvh ? f1 * invh : 0.f;
            }
        }
        float pa = w00[0] + w00[1] + w00[2] + w00[3];
        float pb = 0.f;
        if (big) {
            pa += w10[0] + w10[1] + w10[2] + w10[3];
            pb = w01[0] + w01[1] + w01[2] + w01[3] +
                 w11[0] + w11[1] + w11[2] + w11[3];
        }
        pa += __shfl_xor(pa, 16);
        pa += __shfl_xor(pa, 32);
        if (big) {
            pb += __shfl_xor(pb, 16);
            pb += __shfl_xor(pb, 32);
        }
        cA = pa;  // c_{row}    (0 for row >= L)
        cB = pb;  // c_{16+row} (0 for 16+row >= L)
    }

    // ---- Output: out[s][d] = sum_k c_k * E[start+k][d], k unrolled x4 ----
    if (active) {
        f32x4 o[3] = {};
        const int KP = (L + 3) & ~3;  // <= 32; padded rows in-bounds, c_k = 0
        const __bf16* ebase = Eb + (size_t)start * Dd + lane * 4;
        for (int k = 0; k < KP; k += 4) {
            float cv[4];
            bf16x4 ev[4][3];
#pragma unroll
            for (int j = 0; j < 4; ++j) {
                const int kk = k + j;
                cv[j] = (kk < 16) ? __shfl(cA, kk) : __shfl(cB, kk - 16);
#pragma unroll
                for (int i = 0; i < 3; ++i)
                    ev[j][i] = *reinterpret_cast<const bf16x4*>(ebase + (size_t)kk * Dd + i * 256);
            }
#pragma unroll
            for (int j = 0; j < 4; ++j)
#pragma unroll
                for (int i = 0; i < 3; ++i) {
                    o[i][0] += cv[j] * (float)ev[j][i][0];
                    o[i][1] += cv[j] * (float)ev[j][i][1];
                    o[i][2] += cv[j] * (float)ev[j][i][2];
                    o[i][3] += cv[j] * (float)ev[j][i][3];
                }
        }
#pragma unroll
        for (int i = 0; i < 3; ++i)
            *reinterpret_cast<f32x4*>(&out[(size_t)s * Dd + i * 256 + lane * 4]) = o[i];
    }
}

// ---------------------------------------------------------------------------
extern "C" void kernel_launch(void* const* d_in, const int* in_sizes, int n_in,
                              void* d_out, int out_size, void* d_ws, size_t ws_size,
                              hipStream_t stream) {
    const float* emb   = (const float*)d_in[0];
    const int*   spans = (const int*)d_in[1];
    const float* Wq    = (const float*)d_in[2];
    const float* bq    = (const float*)d_in[3];
    float*       out   = (float*)d_out;

    const size_t TD = (size_t)Tt * Dd;
    const size_t DD = (size_t)Dd * Dd;
    const int nInts = 8192 + 10016;
    const size_t intBytes = (size_t)nInts * sizeof(int);
    auto align16 = [](size_t x) { return (x + 15) & ~(size_t)15; };

    const size_t bfBytes = align16((4 * TD + 2 * DD) * 2);
    const size_t pBytes  = 2 * TD * sizeof(float);
    const size_t needA2 = pBytes + bfBytes + intBytes;   // split-K path
    const size_t needA  = bfBytes + intBytes;            // round-4 path
    const size_t needB  = align16(3 * TD * 2) + intBytes;
    const size_t needC  = 3 * TD * 2;

    if (ws_size >= needA2) {
        float* P = (float*)d_ws;
        __bf16* w = (__bf16*)((char*)d_ws + pBytes);
        __bf16* Qh = w;
        __bf16* Ql = w + TD;
        __bf16* Eh = w + 2 * TD;
        __bf16* El = w + 3 * TD;
        __bf16* Wh = w + 4 * TD;
        __bf16* Wl = Wh + DD;
        int* hist = (int*)((char*)d_ws + pBytes + bfBytes);
        int* perm = hist + 8192;

        conv_kernel<true><<<(int)(TD / 4 + 255) / 256, 256, 0, stream>>>(emb, Eh, El, (int)(TD / 4));
        conv_kernel<true><<<(int)(DD / 4 + 255) / 256, 256, 0, stream>>>(Wq, Wh, Wl, (int)(DD / 4));
        zero_kernel<<<32, 256, 0, stream>>>(hist, 8192);
        hist_kernel<<<40, 256, 0, stream>>>(spans, hist);
        scan_kernel<<<1, 256, 0, stream>>>(hist);
        scatter_kernel<<<40, 256, 0, stream>>>(spans, hist, perm);
        qproj_mfma_splitk_kernel<<<768, 256, 0, stream>>>(Eh, El, Wh, Wl, P);
        qcombine_kernel<<<(int)(TD / 4 / 256), 256, 0, stream>>>(P, bq, Qh, Ql);
        span_attn_kernel<true, true><<<2504, 256, 0, stream>>>(Eh, spans, Qh, Ql, perm, out);
    } else if (ws_size >= needA) {
        __bf16* w = (__bf16*)d_ws;
        __bf16* Qh = w;
        __bf16* Ql = w + TD;
        __bf16* Eh = w + 2 * TD;
        __bf16* El = w + 3 * TD;
        __bf16* Wh = w + 4 * TD;
        __bf16* Wl = Wh + DD;
        int* hist = (int*)((char*)d_ws + bfBytes);
        int* perm = hist + 8192;

        conv_kernel<true><<<(int)(TD / 4 + 255) / 256, 256, 0, stream>>>(emb, Eh, El, (int)(TD / 4));
        conv_kernel<true><<<(int)(DD / 4 + 255) / 256, 256, 0, stream>>>(Wq, Wh, Wl, (int)(DD / 4));
        zero_kernel<<<32, 256, 0, stream>>>(hist, 8192);
        hist_kernel<<<40, 256, 0, stream>>>(spans, hist);
        scan_kernel<<<1, 256, 0, stream>>>(hist);
        scatter_kernel<<<40, 256, 0, stream>>>(spans, hist, perm);
        qproj_mfma_kernel<<<384, 256, 0, stream>>>(Eh, El, Wh, Wl, bq, Qh, Ql);
        span_attn_kernel<true, true><<<2504, 256, 0, stream>>>(Eh, spans, Qh, Ql, perm, out);
    } else if (ws_size >= needB) {
        __bf16* w = (__bf16*)d_ws;
        __bf16* Qh = w;
        __bf16* Ql = w + TD;
        __bf16* Eh = w + 2 * TD;
        int* hist = (int*)((char*)d_ws + align16(3 * TD * 2));
        int* perm = hist + 8192;

        conv_kernel<false><<<(int)(TD / 4 + 255) / 256, 256, 0, stream>>>(emb, Eh, nullptr, (int)(TD / 4));
        zero_kernel<<<32, 256, 0, stream>>>(hist, 8192);
        hist_kernel<<<40, 256, 0, stream>>>(spans, hist);
        scan_kernel<<<1, 256, 0, stream>>>(hist);
        scatter_kernel<<<40, 256, 0, stream>>>(spans, hist, perm);
        qproj_kernel<true><<<dim3(Tt / 64, Dd / 64), 256, 0, stream>>>(emb, Wq, bq, Qh, Ql);
        span_attn_kernel<true, true><<<2504, 256, 0, stream>>>(Eh, spans, Qh, Ql, perm, out);
    } else if (ws_size >= needC) {
        __bf16* w = (__bf16*)d_ws;
        __bf16* Qh = w;
        __bf16* Ql = w + TD;
        __bf16* Eh = w + 2 * TD;
        conv_kernel<false><<<(int)(TD / 4 + 255) / 256, 256, 0, stream>>>(emb, Eh, nullptr, (int)(TD / 4));
        qproj_kernel<true><<<dim3(Tt / 64, Dd / 64), 256, 0, stream>>>(emb, Wq, bq, Qh, Ql);
        span_attn_kernel<true, false><<<2500, 256, 0, stream>>>(Eh, spans, Qh, Ql, nullptr, out);
    } else {
        __bf16* w = (__bf16*)d_ws;
        __bf16* Qh = w;
        __bf16* Eh = w + TD;
        conv_kernel<false><<<(int)(TD / 4 + 255) / 256, 256, 0, stream>>>(emb, Eh, nullptr, (int)(TD / 4));
        qproj_kernel<false><<<dim3(Tt / 64, Dd / 64), 256, 0, stream>>>(emb, Wq, bq, Qh, nullptr);
        span_attn_kernel<false, false><<<2500, 256, 0, stream>>>(Eh, spans, Qh, nullptr, nullptr, out);
    }
}

// Round 6
// 178.807 us; speedup vs baseline: 3.4429x; 1.6558x over previous
//
#include <hip/hip_runtime.h>
#include <hip/hip_bf16.h>
#include <cstddef>
#include <cstdint>

constexpr int Tt = 8192;
constexpr int Dd = 768;
constexpr int Nn = 10000;
constexpr int Ww = 32;

typedef __bf16 bf16x8 __attribute__((ext_vector_type(8)));
typedef __bf16 bf16x4 __attribute__((ext_vector_type(4)));
typedef __bf16 bf16x2 __attribute__((ext_vector_type(2)));
typedef _Float16 half8v __attribute__((ext_vector_type(8)));
typedef _Float16 half4v __attribute__((ext_vector_type(4)));
typedef float f32x4 __attribute__((ext_vector_type(4)));

#define MFMA16(a, b, c) __builtin_amdgcn_mfma_f32_16x16x32_bf16((a), (b), (c), 0, 0, 0)
#define MFMAH(a, b, c) __builtin_amdgcn_mfma_f32_16x16x32_f16((a), (b), (c), 0, 0, 0)

// ---------------------------------------------------------------------------
// fp32 -> bf16 hi (+ optional lo) converter (for Wq / fallback tiers).
// ---------------------------------------------------------------------------
template <bool LO>
__global__ __launch_bounds__(256) void conv_kernel(const float* __restrict__ src,
                                                   __bf16* __restrict__ h,
                                                   __bf16* __restrict__ l, int n4) {
    const int i = blockIdx.x * 256 + threadIdx.x;
    if (i >= n4) return;
    const float4 v = reinterpret_cast<const float4*>(src)[i];
    bf16x4 oh, ol;
    oh[0] = (__bf16)v.x; oh[1] = (__bf16)v.y; oh[2] = (__bf16)v.z; oh[3] = (__bf16)v.w;
    reinterpret_cast<bf16x4*>(h)[i] = oh;
    if (LO) {
        ol[0] = (__bf16)(v.x - (float)oh[0]);
        ol[1] = (__bf16)(v.y - (float)oh[1]);
        ol[2] = (__bf16)(v.z - (float)oh[2]);
        ol[3] = (__bf16)(v.w - (float)oh[3]);
        reinterpret_cast<bf16x4*>(l)[i] = ol;
    }
}

// fp32 -> bf16 hi + bf16 lo + fp16 (emb: qproj inputs + span array).
__global__ __launch_bounds__(256) void conv3_kernel(const float* __restrict__ src,
                                                    __bf16* __restrict__ h,
                                                    __bf16* __restrict__ l,
                                                    _Float16* __restrict__ f, int n4) {
    const int i = blockIdx.x * 256 + threadIdx.x;
    if (i >= n4) return;
    const float4 v = reinterpret_cast<const float4*>(src)[i];
    bf16x4 oh, ol;
    half4v of;
    const float vv[4] = {v.x, v.y, v.z, v.w};
#pragma unroll
    for (int j = 0; j < 4; ++j) {
        oh[j] = (__bf16)vv[j];
        ol[j] = (__bf16)(vv[j] - (float)oh[j]);
        of[j] = (_Float16)vv[j];
    }
    reinterpret_cast<bf16x4*>(h)[i] = oh;
    reinterpret_cast<bf16x4*>(l)[i] = ol;
    reinterpret_cast<half4v*>(f)[i] = of;
}

// ---------------------------------------------------------------------------
// Counting sort of span indices by start. Rebuilt fully every call.
// ---------------------------------------------------------------------------
__global__ __launch_bounds__(256) void zero_kernel(int* __restrict__ p, int n) {
    const int i = blockIdx.x * 256 + threadIdx.x;
    if (i < n) p[i] = 0;
}

__global__ __launch_bounds__(256) void hist_kernel(const int* __restrict__ spans,
                                                   int* __restrict__ hist) {
    const int i = blockIdx.x * 256 + threadIdx.x;
    if (i < Nn) atomicAdd(&hist[spans[2 * i]], 1);
}

__global__ __launch_bounds__(256) void scan_kernel(int* __restrict__ hist) {
    __shared__ int part[256];
    const int t = threadIdx.x;
    int vals[32];
    int sum = 0;
#pragma unroll
    for (int i = 0; i < 32; ++i) { vals[i] = hist[t * 32 + i]; sum += vals[i]; }
    part[t] = sum;
    __syncthreads();
    for (int off = 1; off < 256; off <<= 1) {
        const int v = (t >= off) ? part[t - off] : 0;
        __syncthreads();
        part[t] += v;
        __syncthreads();
    }
    int run = (t == 0) ? 0 : part[t - 1];
#pragma unroll
    for (int i = 0; i < 32; ++i) { const int v = vals[i]; hist[t * 32 + i] = run; run += v; }
}

__global__ __launch_bounds__(256) void scatter_kernel(const int* __restrict__ spans,
                                                      int* __restrict__ offs,
                                                      int* __restrict__ perm) {
    const int i = blockIdx.x * 256 + threadIdx.x;
    if (i < Nn) {
        const int p = atomicAdd(&offs[spans[2 * i]], 1);
        perm[p] = i;
    }
}

// ---------------------------------------------------------------------------
// fp32 vector qproj (fallback tiers). Q = emb @ Wq^T + bq, bf16 hi/lo out.
// ---------------------------------------------------------------------------
template <bool SPLIT>
__global__ __launch_bounds__(256) void qproj_kernel(const float* __restrict__ emb,
                                                    const float* __restrict__ Wq,
                                                    const float* __restrict__ bq,
                                                    __bf16* __restrict__ Qh,
                                                    __bf16* __restrict__ Ql) {
    __shared__ float As[64][32];
    __shared__ float Bs[64][32];
    const int tid = threadIdx.x;
    const int tx = tid & 15;
    const int ty = tid >> 4;
    const int m0 = blockIdx.x * 64;
    const int n0 = blockIdx.y * 64;

    float acc[4][4] = {};

    for (int kc = 0; kc < Dd; kc += 32) {
#pragma unroll
        for (int i = 0; i < 2; ++i) {
            const int f   = tid + i * 256;
            const int row = f >> 3;
            const int c4  = f & 7;
            const int ph  = (c4 + (row >> 2)) & 7;
            *reinterpret_cast<float4*>(&As[row][ph * 4]) =
                *reinterpret_cast<const float4*>(&emb[(size_t)(m0 + row) * Dd + kc + c4 * 4]);
            *reinterpret_cast<float4*>(&Bs[row][ph * 4]) =
                *reinterpret_cast<const float4*>(&Wq[(size_t)(n0 + row) * Dd + kc + c4 * 4]);
        }
        __syncthreads();
#pragma unroll
        for (int d4 = 0; d4 < 8; ++d4) {
            float4 av[4], bv[4];
#pragma unroll
            for (int r = 0; r < 4; ++r)
                av[r] = *reinterpret_cast<const float4*>(&As[ty * 4 + r][((d4 + ty) & 7) * 4]);
#pragma unroll
            for (int c = 0; c < 4; ++c)
                bv[c] = *reinterpret_cast<const float4*>(&Bs[tx * 4 + c][((d4 + tx) & 7) * 4]);
#pragma unroll
            for (int r = 0; r < 4; ++r)
#pragma unroll
                for (int c = 0; c < 4; ++c) {
                    acc[r][c] += av[r].x * bv[c].x;
                    acc[r][c] += av[r].y * bv[c].y;
                    acc[r][c] += av[r].z * bv[c].z;
                    acc[r][c] += av[r].w * bv[c].w;
                }
        }
        __syncthreads();
    }
#pragma unroll
    for (int r = 0; r < 4; ++r) {
        bf16x4 oh, ol;
#pragma unroll
        for (int c = 0; c < 4; ++c) {
            const float v = acc[r][c] + bq[n0 + tx * 4 + c];
            const __bf16 h = (__bf16)v;
            oh[c] = h;
            if (SPLIT) ol[c] = (__bf16)(v - (float)h);
        }
        const size_t off = (size_t)(m0 + ty * 4 + r) * Dd + n0 + tx * 4;
        *reinterpret_cast<bf16x4*>(&Qh[off]) = oh;
        if (SPLIT) *reinterpret_cast<bf16x4*>(&Ql[off]) = ol;
    }
}

// ---------------------------------------------------------------------------
// MFMA qproj v3: 128x64 tile, 768 blocks (3/CU), software-pipelined sync
// staging (next K-tile global->reg loads issued before the MFMA burst),
// 3-term bf16 split internally, fp16 single-array output.
// ---------------------------------------------------------------------------
__global__ __launch_bounds__(256) void qproj_mfma2_kernel(const __bf16* __restrict__ Eh,
                                                          const __bf16* __restrict__ El,
                                                          const __bf16* __restrict__ Wh,
                                                          const __bf16* __restrict__ Wl,
                                                          const float* __restrict__ bq,
                                                          _Float16* __restrict__ Qf) {
    __shared__ __align__(16) __bf16 Ahs[128 * 32];
    __shared__ __align__(16) __bf16 Als[128 * 32];
    __shared__ __align__(16) __bf16 Bhs[64 * 32];
    __shared__ __align__(16) __bf16 Bls[64 * 32];

    const int tid  = threadIdx.x;
    const int wave = tid >> 6;
    const int lane = tid & 63;

    const int b   = blockIdx.x;        // 0..767
    const int xcd = b & 7;
    const int li  = b >> 3;            // 0..95
    const int mt  = xcd * 8 + li / 12; // 0..63
    const int nt  = li % 12;           // 0..11
    const int m0 = mt * 128;
    const int n0 = nt * 64;
    const int wm = (wave & 1) * 64;
    const int wn = (wave >> 1) * 32;
    const int fr = lane & 15;
    const int kg = lane >> 4;

    int arow[2], agc[2];
#pragma unroll
    for (int i = 0; i < 2; ++i) {
        const int seg = tid + i * 256;
        arow[i] = seg >> 2;
        agc[i]  = ((seg & 3) ^ (arow[i] & 3)) * 8;
    }
    const int brow = tid >> 2;
    const int bgc  = ((tid & 3) ^ (brow & 3)) * 8;

    bf16x8 pah[2], pal[2], pbh, pbl;
    auto ldnext = [&](int kc) {
#pragma unroll
        for (int i = 0; i < 2; ++i) {
            const size_t ga = (size_t)(m0 + arow[i]) * Dd + kc + agc[i];
            pah[i] = *reinterpret_cast<const bf16x8*>(&Eh[ga]);
            pal[i] = *reinterpret_cast<const bf16x8*>(&El[ga]);
        }
        const size_t gb = (size_t)(n0 + brow) * Dd + kc + bgc;
        pbh = *reinterpret_cast<const bf16x8*>(&Wh[gb]);
        pbl = *reinterpret_cast<const bf16x8*>(&Wl[gb]);
    };
    ldnext(0);

    f32x4 acc[4][2] = {};

    for (int kc = 0; kc < Dd; kc += 32) {
        __syncthreads();  // previous iteration's LDS reads done
#pragma unroll
        for (int i = 0; i < 2; ++i) {
            const int slot = tid + i * 256;
            *reinterpret_cast<bf16x8*>(&Ahs[slot * 8]) = pah[i];
            *reinterpret_cast<bf16x8*>(&Als[slot * 8]) = pal[i];
        }
        *reinterpret_cast<bf16x8*>(&Bhs[tid * 8]) = pbh;
        *reinterpret_cast<bf16x8*>(&Bls[tid * 8]) = pbl;
        __syncthreads();
        if (kc + 32 < Dd) ldnext(kc + 32);  // overlaps the MFMA burst below

        bf16x8 ah[4], al[4], bh[2], bl[2];
#pragma unroll
        for (int r = 0; r < 4; ++r) {
            const int R = wm + r * 16 + fr;
            const int p = (kg ^ (R & 3)) * 8;
            ah[r] = *reinterpret_cast<const bf16x8*>(&Ahs[R * 32 + p]);
            al[r] = *reinterpret_cast<const bf16x8*>(&Als[R * 32 + p]);
        }
#pragma unroll
        for (int c = 0; c < 2; ++c) {
            const int R = wn + c * 16 + fr;
            const int p = (kg ^ (R & 3)) * 8;
            bh[c] = *reinterpret_cast<const bf16x8*>(&Bhs[R * 32 + p]);
            bl[c] = *reinterpret_cast<const bf16x8*>(&Bls[R * 32 + p]);
        }
#pragma unroll
        for (int r = 0; r < 4; ++r)
#pragma unroll
            for (int c = 0; c < 2; ++c) {
                acc[r][c] = MFMA16(ah[r], bh[c], acc[r][c]);
                acc[r][c] = MFMA16(al[r], bh[c], acc[r][c]);
                acc[r][c] = MFMA16(ah[r], bl[c], acc[r][c]);
            }
    }

#pragma unroll
    for (int c = 0; c < 2; ++c) {
        const int ocol = n0 + wn + c * 16 + fr;
        const float bqv = bq[ocol];
#pragma unroll
        for (int r = 0; r < 4; ++r)
#pragma unroll
            for (int j = 0; j < 4; ++j) {
                const int orow = m0 + wm + r * 16 + kg * 4 + j;
                Qf[(size_t)orow * Dd + ocol] = (_Float16)(acc[r][c][j] + bqv);
            }
    }
}

// ---------------------------------------------------------------------------
// Span attention v3 (fp16, window-shared LDS): block = 4 consecutive sorted
// spans; stage rows [w0, w0+48) in 6 D-chunks of 128 (stride-136 padding);
// MFMA fragments read LDS. Spans not fitting the window (rare) take a
// wave-uniform global-load fallback between the same barriers.
// Softmax + column sums in registers (round-5 proven shfl code).
// ---------------------------------------------------------------------------
__global__ __launch_bounds__(256) void span_attn_win_kernel(const _Float16* __restrict__ Ef,
                                                            const int* __restrict__ spans,
                                                            const _Float16* __restrict__ Qf,
                                                            const int* __restrict__ perm,
                                                            float* __restrict__ out) {
    constexpr int WR = 48, CH = 128, ST = 136, NCH = Dd / CH;
    __shared__ __align__(16) _Float16 Qs[WR * ST];
    __shared__ __align__(16) _Float16 Es[WR * ST];

    const int tid  = threadIdx.x;
    const int wave = tid >> 6;
    const int lane = tid & 63;

    const int b     = blockIdx.x;
    const int bp    = (b & 7) * 313 + (b >> 3);
    const int slot0 = bp * 4;
    const int slot  = slot0 + wave;
    const bool active = slot < Nn;

    int s0 = perm[slot0 < Nn ? slot0 : (Nn - 1)];
    if ((unsigned)s0 >= (unsigned)Nn) s0 = 0;
    int s = active ? perm[slot] : s0;
    if ((unsigned)s >= (unsigned)Nn) s = 0;

    const int w0    = spans[2 * s0];
    const int start = spans[2 * s];
    const int L     = spans[2 * s + 1] - start + 1;  // 1..32
    const bool big  = L > 16;
    const int sl    = start - w0;
    const bool inwin = active && sl >= 0 && sl <= (WR - 32);

    const int row = lane & 15;  // A-frag m; C-col k
    const int kq  = lane >> 4;

    const size_t gq = (size_t)(start + row) * Dd + kq * 8;  // fallback base

    f32x4 acc00 = {0.f, 0.f, 0.f, 0.f};
    f32x4 acc01 = {0.f, 0.f, 0.f, 0.f};
    f32x4 acc10 = {0.f, 0.f, 0.f, 0.f};
    f32x4 acc11 = {0.f, 0.f, 0.f, 0.f};

    for (int c = 0; c < NCH; ++c) {
        const int c0 = c * CH;
        __syncthreads();  // previous chunk's LDS reads complete
#pragma unroll
        for (int i = 0; i < 3; ++i) {
            const int seg = tid + i * 256;  // 768 segs: 48 rows x 16 col-segs
            const int r  = seg >> 4;
            const int cs = seg & 15;
            const int gr = w0 + r < Tt ? w0 + r : Tt - 1;  // clamp (pad rows unused)
            const size_t ga = (size_t)gr * Dd + c0 + cs * 8;
            *reinterpret_cast<half8v*>(&Qs[r * ST + cs * 8]) =
                *reinterpret_cast<const half8v*>(&Qf[ga]);
            *reinterpret_cast<half8v*>(&Es[r * ST + cs * 8]) =
                *reinterpret_cast<const half8v*>(&Ef[ga]);
        }
        __syncthreads();

        if (inwin) {
            const int ab = (sl + row) * ST + kq * 8;
#pragma unroll
            for (int j = 0; j < 4; ++j) {
                const int o = j * 32;
                const half8v a0 = *reinterpret_cast<const half8v*>(&Qs[ab + o]);
                const half8v b0 = *reinterpret_cast<const half8v*>(&Es[ab + o]);
                acc00 = MFMAH(a0, b0, acc00);
                if (big) {
                    const half8v a1 = *reinterpret_cast<const half8v*>(&Qs[ab + 16 * ST + o]);
                    const half8v b1 = *reinterpret_cast<const half8v*>(&Es[ab + 16 * ST + o]);
                    acc01 = MFMAH(a0, b1, acc01);
                    acc10 = MFMAH(a1, b0, acc10);
                    acc11 = MFMAH(a1, b1, acc11);
                }
            }
        } else if (active) {
            // rare: span exceeds window — direct global fragment loads
#pragma unroll
            for (int j = 0; j < 4; ++j) {
                const int o = c0 + j * 32;
                const half8v a0 = *reinterpret_cast<const half8v*>(&Qf[gq + o]);
                const half8v b0 = *reinterpret_cast<const half8v*>(&Ef[gq + o]);
                acc00 = MFMAH(a0, b0, acc00);
                if (big) {
                    const half8v a1 = *reinterpret_cast<const half8v*>(&Qf[gq + 16 * Dd + o]);
                    const half8v b1 = *reinterpret_cast<const half8v*>(&Ef[gq + 16 * Dd + o]);
                    acc01 = MFMAH(a0, b1, acc01);
                    acc10 = MFMAH(a1, b0, acc10);
                    acc11 = MFMAH(a1, b1, acc11);
                }
            }
        }
    }

    // ---- In-register softmax + column sums (round-5 proven) ----
    const float NEG = -1e30f;
    const bool kv0 = row < L;
    const bool kv1 = (16 + row) < L;
    float cA, cB;
    {
        float w00[4], w01[4], w10[4], w11[4];
#pragma unroll
        for (int r = 0; r < 4; ++r) {
            float m = kv0 ? acc00[r] : NEG;
            if (big) m = fmaxf(m, kv1 ? acc01[r] : NEG);
#pragma unroll
            for (int st = 1; st <= 8; st <<= 1) m = fmaxf(m, __shfl_xor(m, st));
            const float e0 = kv0 ? __expf(acc00[r] - m) : 0.f;
            const float e1 = (big && kv1) ? __expf(acc01[r] - m) : 0.f;
            float sum = e0 + e1;
#pragma unroll
            for (int st = 1; st <= 8; st <<= 1) sum += __shfl_xor(sum, st);
            const float inv = 1.f / sum;
            const bool qv = (kq * 4 + r) < L;
            w00[r] = qv ? e0 * inv : 0.f;
            w01[r] = qv ? e1 * inv : 0.f;
            if (big) {
                float mh = kv0 ? acc10[r] : NEG;
                mh = fmaxf(mh, kv1 ? acc11[r] : NEG);
#pragma unroll
                for (int st = 1; st <= 8; st <<= 1) mh = fmaxf(mh, __shfl_xor(mh, st));
                const float f0 = kv0 ? __expf(acc10[r] - mh) : 0.f;
                const float f1 = kv1 ? __expf(acc11[r] - mh) : 0.f;
                float sh = f0 + f1;
#pragma unroll
                for (int st = 1; st <= 8; st <<= 1) sh += __shfl_xor(sh, st);
                const float invh = 1.f / sh;
                const bool qvh = (16 + kq * 4 + r) < L;
                w10[r] = qvh ? f0 * invh : 0.f;
                w11[r] = qvh ? f1 * invh : 0.f;
            }
        }
        float pa = w00[0] + w00[1] + w00[2] + w00[3];
        float pb = 0.f;
        if (big) {
            pa += w10[0] + w10[1] + w10[2] + w10[3];
            pb = w01[0] + w01[1] + w01[2] + w01[3] +
                 w11[0] + w11[1] + w11[2] + w11[3];
        }
        pa += __shfl_xor(pa, 16);
        pa += __shfl_xor(pa, 32);
        if (big) {
            pb += __shfl_xor(pb, 16);
            pb += __shfl_xor(pb, 32);
        }
        cA = pa;
        cB = pb;
    }

    // ---- Output: out[s][d] = sum_k c_k * E[start+k][d], fp16 reads ----
    if (active) {
        f32x4 o[3] = {};
        const int KP = (L + 3) & ~3;
        const _Float16* ebase = Ef + (size_t)start * Dd + lane * 4;
        for (int k = 0; k < KP; k += 4) {
            float cv[4];
            half4v ev[4][3];
#pragma unroll
            for (int j = 0; j < 4; ++j) {
                const int kk = k + j;
                cv[j] = (kk < 16) ? __shfl(cA, kk) : __shfl(cB, kk - 16);
#pragma unroll
                for (int i = 0; i < 3; ++i)
                    ev[j][i] = *reinterpret_cast<const half4v*>(ebase + (size_t)kk * Dd + i * 256);
            }
#pragma unroll
            for (int j = 0; j < 4; ++j)
#pragma unroll
                for (int i = 0; i < 3; ++i) {
                    o[i][0] += cv[j] * (float)ev[j][i][0];
                    o[i][1] += cv[j] * (float)ev[j][i][1];
                    o[i][2] += cv[j] * (float)ev[j][i][2];
                    o[i][3] += cv[j] * (float)ev[j][i][3];
                }
        }
#pragma unroll
        for (int i = 0; i < 3; ++i)
            *reinterpret_cast<f32x4*>(&out[(size_t)s * Dd + i * 256 + lane * 4]) = o[i];
    }
}

// ---------------------------------------------------------------------------
// Round-5 bf16 global span kernel (proven) — fallback tiers only.
// ---------------------------------------------------------------------------
template <bool SPLIT, bool SORTED>
__global__ __launch_bounds__(256) void span_attn_g_kernel(const __bf16* __restrict__ Eb,
                                                          const int* __restrict__ spans,
                                                          const __bf16* __restrict__ Qh,
                                                          const __bf16* __restrict__ Ql,
                                                          const int* __restrict__ perm,
                                                          float* __restrict__ out) {
    const int wave = threadIdx.x >> 6;
    const int lane = threadIdx.x & 63;

    int s;
    bool active;
    if (SORTED) {
        const int b    = blockIdx.x;
        const int bp   = (b & 7) * 313 + (b >> 3);
        const int slot = bp * 4 + wave;
        active = slot < Nn;
        int sv = active ? perm[slot] : 0;
        if ((unsigned)sv >= (unsigned)Nn) sv = 0;
        s = sv;
    } else {
        s = blockIdx.x * 4 + wave;
        active = true;
    }

    const int start = spans[2 * s];
    const int L     = spans[2 * s + 1] - start + 1;
    const bool big  = L > 16;

    const int row = lane & 15;
    const int kq  = lane >> 4;

    const size_t rbase = (size_t)(start + row) * Dd + kq * 8;
    const __bf16* qh0 = Qh + rbase;
    const __bf16* eb0 = Eb + rbase;
    const __bf16* ql0 = SPLIT ? (Ql + rbase) : nullptr;

    f32x4 acc00 = {0.f, 0.f, 0.f, 0.f};
    f32x4 acc01 = {0.f, 0.f, 0.f, 0.f};
    f32x4 acc10 = {0.f, 0.f, 0.f, 0.f};
    f32x4 acc11 = {0.f, 0.f, 0.f, 0.f};

    if (!big) {
        for (int kc = 0; kc < Dd; kc += 128) {
            bf16x8 A[4], B[4], AL[4];
#pragma unroll
            for (int j = 0; j < 4; ++j) {
                const int o = kc + j * 32;
                A[j] = *reinterpret_cast<const bf16x8*>(qh0 + o);
                B[j] = *reinterpret_cast<const bf16x8*>(eb0 + o);
                if (SPLIT) AL[j] = *reinterpret_cast<const bf16x8*>(ql0 + o);
            }
#pragma unroll
            for (int j = 0; j < 4; ++j) {
                acc00 = MFMA16(A[j], B[j], acc00);
                if (SPLIT) acc00 = MFMA16(AL[j], B[j], acc00);
            }
        }
    } else {
        for (int kc = 0; kc < Dd; kc += 64) {
            bf16x8 A0[2], A1[2], B0[2], B1[2], AL0[2], AL1[2];
#pragma unroll
            for (int j = 0; j < 2; ++j) {
                const int o = kc + j * 32;
                A0[j] = *reinterpret_cast<const bf16x8*>(qh0 + o);
                A1[j] = *reinterpret_cast<const bf16x8*>(qh0 + 16 * Dd + o);
                B0[j] = *reinterpret_cast<const bf16x8*>(eb0 + o);
                B1[j] = *reinterpret_cast<const bf16x8*>(eb0 + 16 * Dd + o);
                if (SPLIT) {
                    AL0[j] = *reinterpret_cast<const bf16x8*>(ql0 + o);
                    AL1[j] = *reinterpret_cast<const bf16x8*>(ql0 + 16 * Dd + o);
                }
            }
#pragma unroll
            for (int j = 0; j < 2; ++j) {
                acc00 = MFMA16(A0[j], B0[j], acc00);
                acc01 = MFMA16(A0[j], B1[j], acc01);
                acc10 = MFMA16(A1[j], B0[j], acc10);
                acc11 = MFMA16(A1[j], B1[j], acc11);
                if (SPLIT) {
                    acc00 = MFMA16(AL0[j], B0[j], acc00);
                    acc01 = MFMA16(AL0[j], B1[j], acc01);
                    acc10 = MFMA16(AL1[j], B0[j], acc10);
                    acc11 = MFMA16(AL1[j], B1[j], acc11);
                }
            }
        }
    }

    const float NEG = -1e30f;
    const bool kv0 = row < L;
    const bool kv1 = (16 + row) < L;
    float cA, cB;
    {
        float w00[4], w01[4], w10[4], w11[4];
#pragma unroll
        for (int r = 0; r < 4; ++r) {
            float m = kv0 ? acc00[r] : NEG;
            if (big) m = fmaxf(m, kv1 ? acc01[r] : NEG);
#pragma unroll
            for (int st = 1; st <= 8; st <<= 1) m = fmaxf(m, __shfl_xor(m, st));
            const float e0 = kv0 ? __expf(acc00[r] - m) : 0.f;
            const float e1 = (big && kv1) ? __expf(acc01[r] - m) : 0.f;
            float sum = e0 + e1;
#pragma unroll
            for (int st = 1; st <= 8; st <<= 1) sum += __shfl_xor(sum, st);
            const float inv = 1.f / sum;
            const bool qv = (kq * 4 + r) < L;
            w00[r] = qv ? e0 * inv : 0.f;
            w01[r] = qv ? e1 * inv : 0.f;
            if (big) {
                float mh = kv0 ? acc10[r] : NEG;
                mh = fmaxf(mh, kv1 ? acc11[r] : NEG);
#pragma unroll
                for (int st = 1; st <= 8; st <<= 1) mh = fmaxf(mh, __shfl_xor(mh, st));
                const float f0 = kv0 ? __expf(acc10[r] - mh) : 0.f;
                const float f1 = kv1 ? __expf(acc11[r] - mh) : 0.f;
                float sh = f0 + f1;
#pragma unroll
                for (int st = 1; st <= 8; st <<= 1) sh += __shfl_xor(sh, st);
                const float invh = 1.f / sh;
                const bool qvh = (16 + kq * 4 + r) < L;
                w10[r] = qvh ? f0 * invh : 0.f;
                w11[r] = qvh ? f1 * invh : 0.f;
            }
        }
        float pa = w00[0] + w00[1] + w00[2] + w00[3];
        float pb = 0.f;
        if (big) {
            pa += w10[0] + w10[1] + w10[2] + w10[3];
            pb = w01[0] + w01[1] + w01[2] + w01[3] +
                 w11[0] + w11[1] + w11[2] + w11[3];
        }
        pa += __shfl_xor(pa, 16);
        pa += __shfl_xor(pa, 32);
        if (big) {
            pb += __shfl_xor(pb, 16);
            pb += __shfl_xor(pb, 32);
        }
        cA = pa;
        cB = pb;
    }

    if (active) {
        f32x4 o[3] = {};
        const int KP = (L + 3) & ~3;
        const __bf16* ebase = Eb + (size_t)start * Dd + lane * 4;
        for (int k = 0; k < KP; k += 4) {
            float cv[4];
            bf16x4 ev[4][3];
#pragma unroll
            for (int j = 0; j < 4; ++j) {
                const int kk = k + j;
                cv[j] = (kk < 16) ? __shfl(cA, kk) : __shfl(cB, kk - 16);
#pragma unroll
                for (int i = 0; i < 3; ++i)
                    ev[j][i] = *reinterpret_cast<const bf16x4*>(ebase + (size_t)kk * Dd + i * 256);
            }
#pragma unroll
            for (int j = 0; j < 4; ++j)
#pragma unroll
                for (int i = 0; i < 3; ++i) {
                    o[i][0] += cv[j] * (float)ev[j][i][0];
                    o[i][1] += cv[j] * (float)ev[j][i][1];
                    o[i][2] += cv[j] * (float)ev[j][i][2];
                    o[i][3] += cv[j] * (float)ev[j][i][3];
                }
        }
#pragma unroll
        for (int i = 0; i < 3; ++i)
            *reinterpret_cast<f32x4*>(&out[(size_t)s * Dd + i * 256 + lane * 4]) = o[i];
    }
}

// ---------------------------------------------------------------------------
extern "C" void kernel_launch(void* const* d_in, const int* in_sizes, int n_in,
                              void* d_out, int out_size, void* d_ws, size_t ws_size,
                              hipStream_t stream) {
    const float* emb   = (const float*)d_in[0];
    const int*   spans = (const int*)d_in[1];
    const float* Wq    = (const float*)d_in[2];
    const float* bq    = (const float*)d_in[3];
    float*       out   = (float*)d_out;

    const size_t TD = (size_t)Tt * Dd;
    const size_t DD = (size_t)Dd * Dd;
    const int nInts = 8192 + 10016;
    const size_t intBytes = (size_t)nInts * sizeof(int);
    auto align16 = [](size_t x) { return (x + 15) & ~(size_t)15; };

    const size_t mainBf = align16((4 * TD + 2 * DD) * 2);
    const size_t needMain = mainBf + intBytes;
    const size_t needB = align16(3 * TD * 2) + intBytes;
    const size_t needC = 3 * TD * 2;

    if (ws_size >= needMain) {
        char* base = (char*)d_ws;
        _Float16* Qf = (_Float16*)base;
        _Float16* Ef = (_Float16*)(base + TD * 2);
        __bf16* Eh = (__bf16*)(base + 2 * TD * 2);
        __bf16* El = (__bf16*)(base + 3 * TD * 2);
        __bf16* Wh = (__bf16*)(base + 4 * TD * 2);
        __bf16* Wl = (__bf16*)(base + 4 * TD * 2 + DD * 2);
        int* hist = (int*)(base + mainBf);
        int* perm = hist + 8192;

        conv3_kernel<<<(int)(TD / 4 / 256), 256, 0, stream>>>(emb, Eh, El, Ef, (int)(TD / 4));
        conv_kernel<true><<<(int)(DD / 4 / 256), 256, 0, stream>>>(Wq, Wh, Wl, (int)(DD / 4));
        zero_kernel<<<(nInts + 255) / 256, 256, 0, stream>>>(hist, nInts);
        hist_kernel<<<40, 256, 0, stream>>>(spans, hist);
        scan_kernel<<<1, 256, 0, stream>>>(hist);
        scatter_kernel<<<40, 256, 0, stream>>>(spans, hist, perm);
        qproj_mfma2_kernel<<<768, 256, 0, stream>>>(Eh, El, Wh, Wl, bq, Qf);
        span_attn_win_kernel<<<2504, 256, 0, stream>>>(Ef, spans, Qf, perm, out);
    } else if (ws_size >= needB) {
        __bf16* w = (__bf16*)d_ws;
        __bf16* Qh = w;
        __bf16* Ql = w + TD;
        __bf16* Eh = w + 2 * TD;
        int* hist = (int*)((char*)d_ws + align16(3 * TD * 2));
        int* perm = hist + 8192;

        conv_kernel<false><<<(int)(TD / 4 / 256), 256, 0, stream>>>(emb, Eh, nullptr, (int)(TD / 4));
        zero_kernel<<<(nInts + 255) / 256, 256, 0, stream>>>(hist, nInts);
        hist_kernel<<<40, 256, 0, stream>>>(spans, hist);
        scan_kernel<<<1, 256, 0, stream>>>(hist);
        scatter_kernel<<<40, 256, 0, stream>>>(spans, hist, perm);
        qproj_kernel<true><<<dim3(Tt / 64, Dd / 64), 256, 0, stream>>>(emb, Wq, bq, Qh, Ql);
        span_attn_g_kernel<true, true><<<2504, 256, 0, stream>>>(Eh, spans, Qh, Ql, perm, out);
    } else if (ws_size >= needC) {
        __bf16* w = (__bf16*)d_ws;
        __bf16* Qh = w;
        __bf16* Ql = w + TD;
        __bf16* Eh = w + 2 * TD;
        conv_kernel<false><<<(int)(TD / 4 / 256), 256, 0, stream>>>(emb, Eh, nullptr, (int)(TD / 4));
        qproj_kernel<true><<<dim3(Tt / 64, Dd / 64), 256, 0, stream>>>(emb, Wq, bq, Qh, Ql);
        span_attn_g_kernel<true, false><<<2500, 256, 0, stream>>>(Eh, spans, Qh, Ql, nullptr, out);
    } else {
        __bf16* w = (__bf16*)d_ws;
        __bf16* Qh = w;
        __bf16* Eh = w + TD;
        conv_kernel<false><<<(int)(TD / 4 / 256), 256, 0, stream>>>(emb, Eh, nullptr, (int)(TD / 4));
        qproj_kernel<false><<<dim3(Tt / 64, Dd / 64), 256, 0, stream>>>(emb, Wq, bq, Qh, nullptr);
        span_attn_g_kernel<false, false><<<2500, 256, 0, stream>>>(Eh, spans, Qh, nullptr, nullptr, out);
    }
}